// Round 1
// baseline (353.138 us; speedup 1.0000x reference)
//
#include <hip/hip_runtime.h>
#include <hip/hip_bf16.h>
#include <stdint.h>

// Problem constants
#define DM    2048
#define NH    16
#define NKVH  4
#define HD    128
#define WIN   512
#define SEQL  2048
#define BAT   2
#define MR    (BAT*SEQL)        // 4096 rows
#define NQKV  3072              // 2048 q + 512 k + 512 v
#define QKSCALE 0.08838834764831845f
#define CAP   50.0f

typedef unsigned short u16;
typedef __attribute__((ext_vector_type(8))) short short8;
typedef __attribute__((ext_vector_type(4))) float f32x4;

__device__ __forceinline__ u16 f2bf(float f) {
  union { float f; uint32_t u; } v; v.f = f;
  uint32_t r = v.u + 0x7FFFu + ((v.u >> 16) & 1u);
  return (u16)(r >> 16);
}
__device__ __forceinline__ float bf2f(u16 h) {
  union { uint32_t u; float f; } v; v.u = ((uint32_t)h) << 16; return v.f;
}
__device__ __forceinline__ void gld16(const void* g, void* l) {
  __builtin_amdgcn_global_load_lds((const __attribute__((address_space(1))) void*)g,
                                   (__attribute__((address_space(3))) void*)l,
                                   16, 0, 0);
}
__device__ __forceinline__ float softcap_f(float v) {
  float x = v * (1.0f / CAP);
  x = fminf(fmaxf(x, -15.f), 15.f);
  float e = __expf(2.0f * x);
  return CAP * ((e - 1.0f) / (e + 1.0f));
}

// ---------------- elementwise: fp32 -> bf16 cast (float4 vectorized) ----------------
__global__ void k_cast(const float* __restrict__ src, u16* __restrict__ dst, int n4) {
  int i = blockIdx.x * 256 + threadIdx.x;
  if (i >= n4) return;
  float4 v = ((const float4*)src)[i];
  ushort4 o;
  o.x = f2bf(v.x); o.y = f2bf(v.y); o.z = f2bf(v.z); o.w = f2bf(v.w);
  ((ushort4*)dst)[i] = o;
}

// ---------------- RoPE cos/sin table: [S][64] ----------------
__global__ void k_rope_table(float* __restrict__ c, float* __restrict__ sn) {
  int s = blockIdx.x, i = threadIdx.x; // i in [0,64)
  // inv_freq = theta^(-i/64), theta=10000; ln(10000)=9.210340371976184
  float invf = expf(-(float)i * (9.210340371976184f / 64.0f));
  float a = (float)s * invf;
  c[(s << 6) + i]  = cosf(a);
  sn[(s << 6) + i] = sinf(a);
}

// ---------------- GEMM: C[M][N] = A[M][K] * B[N][K]^T, bf16 in, f32 acc ----------------
// m97 structure: 128x128 tile, BK=64, 4 waves (2x2), global_load_lds w=16, 2-phase dbuf.
template <typename OutT>
__global__ __launch_bounds__(256, 2) void k_gemm_bt(const u16* __restrict__ A,
                                                    const u16* __restrict__ Bm,
                                                    OutT* __restrict__ C,
                                                    int N, int K) {
  __shared__ __align__(16) u16 ldsA[2][128 * 64];
  __shared__ __align__(16) u16 ldsB[2][128 * 64];
  const int t = threadIdx.x;
  const int bn = blockIdx.x, bm = blockIdx.y;
  const int m0 = bm * 128, n0 = bn * 128;
  const int row = t >> 3, colb = (t & 7) << 3;     // staging: 8 threads/row, 16B each
  const int lane = t & 63, wid = t >> 6;
  const int lr = lane & 15, lk = lane >> 4;
  const int wr = (wid >> 1) * 64, wc = (wid & 1) * 64;
  const int nt = K >> 6;

  { // prologue: stage tile 0
    const u16* ga = A  + (size_t)(m0 + row) * K + colb;
    const u16* gb = Bm + (size_t)(n0 + row) * K + colb;
    #pragma unroll
    for (int i = 0; i < 4; ++i) {
      gld16(ga + (size_t)i * 32 * K, &ldsA[0][(i * 32 + row) * 64 + colb]);
      gld16(gb + (size_t)i * 32 * K, &ldsB[0][(i * 32 + row) * 64 + colb]);
    }
  }
  __syncthreads();

  f32x4 acc[4][4];
  #pragma unroll
  for (int mi = 0; mi < 4; ++mi)
    #pragma unroll
    for (int ni = 0; ni < 4; ++ni) acc[mi][ni] = f32x4{0.f, 0.f, 0.f, 0.f};

  for (int kt = 0; kt < nt; ++kt) {
    const int cur = kt & 1;
    if (kt + 1 < nt) { // issue next-tile loads before compute
      const int k1 = (kt + 1) << 6, nxt = cur ^ 1;
      const u16* ga = A  + (size_t)(m0 + row) * K + k1 + colb;
      const u16* gb = Bm + (size_t)(n0 + row) * K + k1 + colb;
      #pragma unroll
      for (int i = 0; i < 4; ++i) {
        gld16(ga + (size_t)i * 32 * K, &ldsA[nxt][(i * 32 + row) * 64 + colb]);
        gld16(gb + (size_t)i * 32 * K, &ldsB[nxt][(i * 32 + row) * 64 + colb]);
      }
    }
    const u16* la = ldsA[cur];
    const u16* lb = ldsB[cur];
    #pragma unroll
    for (int ks = 0; ks < 2; ++ks) {
      short8 af[4], bfv[4];
      #pragma unroll
      for (int mi = 0; mi < 4; ++mi)
        af[mi] = *(const short8*)(la + (wr + mi * 16 + lr) * 64 + ks * 32 + lk * 8);
      #pragma unroll
      for (int ni = 0; ni < 4; ++ni)
        bfv[ni] = *(const short8*)(lb + (wc + ni * 16 + lr) * 64 + ks * 32 + lk * 8);
      #pragma unroll
      for (int mi = 0; mi < 4; ++mi)
        #pragma unroll
        for (int ni = 0; ni < 4; ++ni)
          acc[mi][ni] = __builtin_amdgcn_mfma_f32_16x16x32_bf16(af[mi], bfv[ni], acc[mi][ni], 0, 0, 0);
    }
    __syncthreads();
  }

  // epilogue: C/D layout col=lane&15, row=(lane>>4)*4+reg  [m89-verified]
  #pragma unroll
  for (int mi = 0; mi < 4; ++mi) {
    #pragma unroll
    for (int ni = 0; ni < 4; ++ni) {
      const int r0 = m0 + wr + mi * 16 + lk * 4;
      const int c  = n0 + wc + ni * 16 + lr;
      #pragma unroll
      for (int r = 0; r < 4; ++r) {
        float v = acc[mi][ni][r];
        if constexpr (__is_same(OutT, float)) C[(size_t)(r0 + r) * N + c] = v;
        else                                  C[(size_t)(r0 + r) * N + c] = f2bf(v);
      }
    }
  }
}

// ---------------- RoPE on Q: Cqkv[m][h*128+d] -> qr[b][h][s][d] ----------------
__global__ void k_rope_q(const u16* __restrict__ C, const float* __restrict__ cosT,
                         const float* __restrict__ sinT, u16* __restrict__ qr) {
  int idx = blockIdx.x * 256 + threadIdx.x;   // 4096*16*64
  int i = idx & 63, hh = (idx >> 6) & 15, m = idx >> 10;
  int s = m & (SEQL - 1), b = m >> 11;
  size_t cb = (size_t)m * NQKV + hh * HD + i;
  float x1 = bf2f(C[cb]), x2 = bf2f(C[cb + 64]);
  float c = cosT[(s << 6) + i], sn = sinT[(s << 6) + i];
  size_t ob = ((size_t)(b * NH + hh) * SEQL + s) * HD + i;
  qr[ob]      = f2bf(x1 * c - x2 * sn);
  qr[ob + 64] = f2bf(x2 * c + x1 * sn);
}

// ---------------- RoPE on K: Cqkv[m][2048+kvh*128+d] -> kr[b][kvh][s][d] ----------------
__global__ void k_rope_k(const u16* __restrict__ C, const float* __restrict__ cosT,
                         const float* __restrict__ sinT, u16* __restrict__ kr) {
  int idx = blockIdx.x * 256 + threadIdx.x;   // 4096*4*64
  int i = idx & 63, kvh = (idx >> 6) & 3, m = idx >> 8;
  int s = m & (SEQL - 1), b = m >> 11;
  size_t cb = (size_t)m * NQKV + 2048 + kvh * HD + i;
  float x1 = bf2f(C[cb]), x2 = bf2f(C[cb + 64]);
  float c = cosT[(s << 6) + i], sn = sinT[(s << 6) + i];
  size_t ob = ((size_t)(b * NKVH + kvh) * SEQL + s) * HD + i;
  kr[ob]      = f2bf(x1 * c - x2 * sn);
  kr[ob + 64] = f2bf(x2 * c + x1 * sn);
}

// ---------------- V transpose: Cqkv[m][2560+kvh*128+d] -> vt[b][kvh][d][s] ----------------
// coalesced writes; strided 2B reads amortized by L2 line reuse across d-neighbors
__global__ void k_vt(const u16* __restrict__ C, u16* __restrict__ vt) {
  int idx = blockIdx.x * 256 + threadIdx.x;   // 2*4*128*2048; bits: b|kvh|d|s
  int s = idx & (SEQL - 1);
  int d = (idx >> 11) & 127;
  int kvh = (idx >> 18) & 3;
  int b = idx >> 20;
  int m = b * SEQL + s;
  vt[idx] = C[(size_t)m * NQKV + 2560 + kvh * HD + d];
}

// ---------------- flash attention: window=512, softcap, GQA ----------------
// 4 waves/block; wave handles 16 q rows. QK^T + PV via 16x16x32 MFMA.
// K, V^T read direct from global (L2/L3-fit, guide CM#7); P transposed via per-wave LDS.
__global__ __launch_bounds__(256) void k_attn(const u16* __restrict__ qr,
                                              const u16* __restrict__ kr,
                                              const u16* __restrict__ vt,
                                              u16* __restrict__ ao) {
  __shared__ __align__(16) u16 plds[4][16][32];
  const int t = threadIdx.x;
  const int wid = t >> 6, lane = t & 63, lr = lane & 15, lk = lane >> 4;
  const int bq = blockIdx.x, h = blockIdx.y, b = blockIdx.z;
  const int kvh = h >> 2;                      // groups = 4
  const int q0 = bq * 64 + wid * 16;
  const u16* qb = qr + (size_t)(b * NH + h) * SEQL * HD;
  const u16* kb = kr + (size_t)(b * NKVH + kvh) * SEQL * HD;
  const u16* vb = vt + (size_t)(b * NKVH + kvh) * HD * SEQL;

  short8 qf[4];
  #pragma unroll
  for (int kc = 0; kc < 4; ++kc)
    qf[kc] = *(const short8*)(qb + (size_t)(q0 + lr) * HD + kc * 32 + lk * 8);

  f32x4 o[8];
  #pragma unroll
  for (int dt = 0; dt < 8; ++dt) o[dt] = f32x4{0.f, 0.f, 0.f, 0.f};
  float mrow[4], lrow[4];
  #pragma unroll
  for (int r = 0; r < 4; ++r) { mrow[r] = -INFINITY; lrow[r] = 0.f; }

  int lo = q0 - (WIN - 1); if (lo < 0) lo = 0;
  const int ktlo = lo >> 5, kthi = (q0 + 15) >> 5;

  for (int kt = ktlo; kt <= kthi; ++kt) {
    const int kv0 = kt << 5;
    f32x4 sv0 = f32x4{0.f, 0.f, 0.f, 0.f}, sv1 = sv0;
    { // QK^T: S[q][kv], A=Q frag, B=K row-frags (B^T pattern)
      const u16* kp0 = kb + (size_t)(kv0 + lr) * HD + lk * 8;
      const u16* kp1 = kb + (size_t)(kv0 + 16 + lr) * HD + lk * 8;
      #pragma unroll
      for (int kc = 0; kc < 4; ++kc) {
        sv0 = __builtin_amdgcn_mfma_f32_16x16x32_bf16(qf[kc], *(const short8*)(kp0 + kc * 32), sv0, 0, 0, 0);
        sv1 = __builtin_amdgcn_mfma_f32_16x16x32_bf16(qf[kc], *(const short8*)(kp1 + kc * 32), sv1, 0, 0, 0);
      }
    }
    #pragma unroll
    for (int r = 0; r < 4; ++r) {
      const int qg = q0 + lk * 4 + r;
      float v0 = softcap_f(sv0[r] * QKSCALE);
      float v1 = softcap_f(sv1[r] * QKSCALE);
      const int kg0 = kv0 + lr, kg1 = kv0 + 16 + lr;
      if (!(kg0 <= qg && kg0 > qg - WIN)) v0 = -1e30f;
      if (!(kg1 <= qg && kg1 > qg - WIN)) v1 = -1e30f;
      float best = fmaxf(v0, v1);
      best = fmaxf(best, __shfl_xor(best, 1));
      best = fmaxf(best, __shfl_xor(best, 2));
      best = fmaxf(best, __shfl_xor(best, 4));
      best = fmaxf(best, __shfl_xor(best, 8));
      float mnew = fmaxf(mrow[r], best);
      float alpha = __expf(mrow[r] - mnew);
      mrow[r] = mnew;
      float p0 = (v0 > -1e29f) ? __expf(v0 - mnew) : 0.f;  // guard all-masked tiles
      float p1 = (v1 > -1e29f) ? __expf(v1 - mnew) : 0.f;
      plds[wid][lk * 4 + r][lr]      = f2bf(p0);
      plds[wid][lk * 4 + r][16 + lr] = f2bf(p1);
      float rs = p0 + p1;
      rs += __shfl_xor(rs, 1); rs += __shfl_xor(rs, 2);
      rs += __shfl_xor(rs, 4); rs += __shfl_xor(rs, 8);
      lrow[r] = lrow[r] * alpha + rs;
      #pragma unroll
      for (int dt = 0; dt < 8; ++dt) o[dt][r] *= alpha;
    }
    // PV: A = P (from LDS, a-frag layout), B = V^T rows (contiguous kv)
    short8 pf = *(const short8*)&plds[wid][lr][lk * 8];
    #pragma unroll
    for (int dt = 0; dt < 8; ++dt) {
      const u16* vp = vb + (size_t)(dt * 16 + lr) * SEQL + kv0 + lk * 8;
      o[dt] = __builtin_amdgcn_mfma_f32_16x16x32_bf16(pf, *(const short8*)vp, o[dt], 0, 0, 0);
    }
  }
  #pragma unroll
  for (int r = 0; r < 4; ++r) {
    float inv = 1.0f / lrow[r];
    const int srow = q0 + lk * 4 + r;
    u16* op = ao + (size_t)(b * SEQL + srow) * DM + h * HD;
    #pragma unroll
    for (int dt = 0; dt < 8; ++dt) op[dt * 16 + lr] = f2bf(o[dt][r] * inv);
  }
}

extern "C" void kernel_launch(void* const* d_in, const int* in_sizes, int n_in,
                              void* d_out, int out_size, void* d_ws, size_t ws_size,
                              hipStream_t stream) {
  (void)in_sizes; (void)n_in; (void)out_size; (void)ws_size;
  const float* hs = (const float*)d_in[0];
  const float* wq = (const float*)d_in[1];
  const float* wk = (const float*)d_in[2];
  const float* wv = (const float*)d_in[3];
  const float* wo = (const float*)d_in[4];
  float* out = (float*)d_out;

  // workspace layout (u16 elems), ~81 MB total
  u16* ws    = (u16*)d_ws;
  u16* A_bf  = ws;                      //  8,388,608  hs bf16 [4096][2048]
  u16* Wqkv  = A_bf + 8388608;          //  6,291,456  packed [3072][2048]
  u16* Cqkv  = Wqkv + 6291456;          // 12,582,912  [4096][3072]
  u16* q_r   = Cqkv + 12582912;         //  8,388,608  [b][h][s][128]
  u16* k_r   = q_r + 8388608;           //  2,097,152  [b][kvh][s][128]
  u16* vTb   = k_r + 2097152;           //  2,097,152  [b][kvh][128][s]
  float* cosT = (float*)(vTb + 2097152);
  float* sinT = cosT + 131072;
  u16* Wo   = Cqkv;                     // reuse Cqkv after rope/vt consume it
  u16* aout = A_bf;                     // reuse A_bf after QKV gemm

  k_cast<<<8192, 256, 0, stream>>>(hs, A_bf, 2097152);
  k_cast<<<4096, 256, 0, stream>>>(wq, Wqkv, 1048576);
  k_cast<<<1024, 256, 0, stream>>>(wk, Wqkv + 4194304, 262144);
  k_cast<<<1024, 256, 0, stream>>>(wv, Wqkv + 5242880, 262144);
  k_rope_table<<<2048, 64, 0, stream>>>(cosT, sinT);

  k_gemm_bt<u16><<<dim3(NQKV / 128, MR / 128), 256, 0, stream>>>(A_bf, Wqkv, Cqkv, NQKV, DM);

  k_rope_q<<<16384, 256, 0, stream>>>(Cqkv, cosT, sinT, q_r);
  k_rope_k<<<4096, 256, 0, stream>>>(Cqkv, cosT, sinT, k_r);
  k_vt<<<8192, 256, 0, stream>>>(Cqkv, vTb);
  k_cast<<<4096, 256, 0, stream>>>(wo, Wo, 1048576);

  k_attn<<<dim3(SEQL / 64, NH, BAT), 256, 0, stream>>>(q_r, k_r, vTb, aout);

  k_gemm_bt<float><<<dim3(DM / 128, MR / 128), 256, 0, stream>>>(aout, Wo, out, DM, DM);
}

// Round 2
// 255.258 us; speedup vs baseline: 1.3835x; 1.3835x over previous
//
#include <hip/hip_runtime.h>
#include <hip/hip_bf16.h>
#include <stdint.h>

// Problem constants
#define DM    2048
#define NH    16
#define NKVH  4
#define HD    128
#define WIN   512
#define SEQL  2048
#define BAT   2
#define MR    (BAT*SEQL)        // 4096 rows
#define NQKV  3072              // 2048 q + 512 k + 512 v
#define QKSCALE 0.08838834764831845f
#define CAP   50.0f

typedef unsigned short u16;
typedef __attribute__((ext_vector_type(8))) short short8;
typedef __attribute__((ext_vector_type(4))) float f32x4;

__device__ __forceinline__ u16 f2bf(float f) {
  union { float f; uint32_t u; } v; v.f = f;
  uint32_t r = v.u + 0x7FFFu + ((v.u >> 16) & 1u);
  return (u16)(r >> 16);
}
__device__ __forceinline__ float bf2f(u16 h) {
  union { uint32_t u; float f; } v; v.u = ((uint32_t)h) << 16; return v.f;
}
__device__ __forceinline__ void gld16(const void* g, void* l) {
  __builtin_amdgcn_global_load_lds((const __attribute__((address_space(1))) void*)g,
                                   (__attribute__((address_space(3))) void*)l,
                                   16, 0, 0);
}
__device__ __forceinline__ float softcap_f(float v) {
  float x = v * (1.0f / CAP);
  x = fminf(fmaxf(x, -15.f), 15.f);
  float e = __expf(2.0f * x);
  return CAP * ((e - 1.0f) / (e + 1.0f));
}

// ---------------- elementwise: fp32 -> bf16 cast (float4 vectorized) ----------------
__global__ void k_cast(const float* __restrict__ src, u16* __restrict__ dst, int n4) {
  int i = blockIdx.x * 256 + threadIdx.x;
  if (i >= n4) return;
  float4 v = ((const float4*)src)[i];
  ushort4 o;
  o.x = f2bf(v.x); o.y = f2bf(v.y); o.z = f2bf(v.z); o.w = f2bf(v.w);
  ((ushort4*)dst)[i] = o;
}

// ---------------- RoPE cos/sin table: [S][64] ----------------
__global__ void k_rope_table(float* __restrict__ c, float* __restrict__ sn) {
  int s = blockIdx.x, i = threadIdx.x; // i in [0,64)
  float invf = expf(-(float)i * (9.210340371976184f / 64.0f));
  float a = (float)s * invf;
  c[(s << 6) + i]  = cosf(a);
  sn[(s << 6) + i] = sinf(a);
}

// ---------------- GEMM: C[M][N] = A[M][K] * B[N][K]^T, bf16 in, f32 acc ----------------
template <typename OutT>
__global__ __launch_bounds__(256, 2) void k_gemm_bt(const u16* __restrict__ A,
                                                    const u16* __restrict__ Bm,
                                                    OutT* __restrict__ C,
                                                    int N, int K) {
  __shared__ __align__(16) u16 ldsA[2][128 * 64];
  __shared__ __align__(16) u16 ldsB[2][128 * 64];
  const int t = threadIdx.x;
  const int bn = blockIdx.x, bm = blockIdx.y;
  const int m0 = bm * 128, n0 = bn * 128;
  const int row = t >> 3, colb = (t & 7) << 3;
  const int lane = t & 63, wid = t >> 6;
  const int lr = lane & 15, lk = lane >> 4;
  const int wr = (wid >> 1) * 64, wc = (wid & 1) * 64;
  const int nt = K >> 6;

  {
    const u16* ga = A  + (size_t)(m0 + row) * K + colb;
    const u16* gb = Bm + (size_t)(n0 + row) * K + colb;
    #pragma unroll
    for (int i = 0; i < 4; ++i) {
      gld16(ga + (size_t)i * 32 * K, &ldsA[0][(i * 32 + row) * 64 + colb]);
      gld16(gb + (size_t)i * 32 * K, &ldsB[0][(i * 32 + row) * 64 + colb]);
    }
  }
  __syncthreads();

  f32x4 acc[4][4];
  #pragma unroll
  for (int mi = 0; mi < 4; ++mi)
    #pragma unroll
    for (int ni = 0; ni < 4; ++ni) acc[mi][ni] = f32x4{0.f, 0.f, 0.f, 0.f};

  for (int kt = 0; kt < nt; ++kt) {
    const int cur = kt & 1;
    if (kt + 1 < nt) {
      const int k1 = (kt + 1) << 6, nxt = cur ^ 1;
      const u16* ga = A  + (size_t)(m0 + row) * K + k1 + colb;
      const u16* gb = Bm + (size_t)(n0 + row) * K + k1 + colb;
      #pragma unroll
      for (int i = 0; i < 4; ++i) {
        gld16(ga + (size_t)i * 32 * K, &ldsA[nxt][(i * 32 + row) * 64 + colb]);
        gld16(gb + (size_t)i * 32 * K, &ldsB[nxt][(i * 32 + row) * 64 + colb]);
      }
    }
    const u16* la = ldsA[cur];
    const u16* lb = ldsB[cur];
    #pragma unroll
    for (int ks = 0; ks < 2; ++ks) {
      short8 af[4], bfv[4];
      #pragma unroll
      for (int mi = 0; mi < 4; ++mi)
        af[mi] = *(const short8*)(la + (wr + mi * 16 + lr) * 64 + ks * 32 + lk * 8);
      #pragma unroll
      for (int ni = 0; ni < 4; ++ni)
        bfv[ni] = *(const short8*)(lb + (wc + ni * 16 + lr) * 64 + ks * 32 + lk * 8);
      #pragma unroll
      for (int mi = 0; mi < 4; ++mi)
        #pragma unroll
        for (int ni = 0; ni < 4; ++ni)
          acc[mi][ni] = __builtin_amdgcn_mfma_f32_16x16x32_bf16(af[mi], bfv[ni], acc[mi][ni], 0, 0, 0);
    }
    __syncthreads();
  }

  #pragma unroll
  for (int mi = 0; mi < 4; ++mi) {
    #pragma unroll
    for (int ni = 0; ni < 4; ++ni) {
      const int r0 = m0 + wr + mi * 16 + lk * 4;
      const int c  = n0 + wc + ni * 16 + lr;
      #pragma unroll
      for (int r = 0; r < 4; ++r) {
        float v = acc[mi][ni][r];
        if constexpr (__is_same(OutT, float)) C[(size_t)(r0 + r) * N + c] = v;
        else                                  C[(size_t)(r0 + r) * N + c] = f2bf(v);
      }
    }
  }
}

// ---------------- RoPE on Q ----------------
__global__ void k_rope_q(const u16* __restrict__ C, const float* __restrict__ cosT,
                         const float* __restrict__ sinT, u16* __restrict__ qr) {
  int idx = blockIdx.x * 256 + threadIdx.x;
  int i = idx & 63, hh = (idx >> 6) & 15, m = idx >> 10;
  int s = m & (SEQL - 1), b = m >> 11;
  size_t cb = (size_t)m * NQKV + hh * HD + i;
  float x1 = bf2f(C[cb]), x2 = bf2f(C[cb + 64]);
  float c = cosT[(s << 6) + i], sn = sinT[(s << 6) + i];
  size_t ob = ((size_t)(b * NH + hh) * SEQL + s) * HD + i;
  qr[ob]      = f2bf(x1 * c - x2 * sn);
  qr[ob + 64] = f2bf(x2 * c + x1 * sn);
}

// ---------------- RoPE on K ----------------
__global__ void k_rope_k(const u16* __restrict__ C, const float* __restrict__ cosT,
                         const float* __restrict__ sinT, u16* __restrict__ kr) {
  int idx = blockIdx.x * 256 + threadIdx.x;
  int i = idx & 63, kvh = (idx >> 6) & 3, m = idx >> 8;
  int s = m & (SEQL - 1), b = m >> 11;
  size_t cb = (size_t)m * NQKV + 2048 + kvh * HD + i;
  float x1 = bf2f(C[cb]), x2 = bf2f(C[cb + 64]);
  float c = cosT[(s << 6) + i], sn = sinT[(s << 6) + i];
  size_t ob = ((size_t)(b * NKVH + kvh) * SEQL + s) * HD + i;
  kr[ob]      = f2bf(x1 * c - x2 * sn);
  kr[ob + 64] = f2bf(x2 * c + x1 * sn);
}

// ---------------- V transpose: Cqkv[m][2560+kvh*128+d] -> vt[b][kvh][d][s] ----------------
__global__ void k_vt(const u16* __restrict__ C, u16* __restrict__ vt) {
  int idx = blockIdx.x * 256 + threadIdx.x;
  int s = idx & (SEQL - 1);
  int d = (idx >> 11) & 127;
  int kvh = (idx >> 18) & 3;
  int b = idx >> 20;
  int m = b * SEQL + s;
  vt[idx] = C[(size_t)m * NQKV + 2560 + kvh * HD + d];
}

// ---------------- flash attention: window=512, softcap, GQA ----------------
// Swapped QK^T (S^T = mfma(K,Q)): each lane owns q-row = lane&15 -> softmax needs
// only 2 shfl_xor per reduction. K and V^T tiles cooperatively staged into LDS
// (global_load_lds w=16, double-buffered, XOR-swizzled per rule #21: linear dest +
// inverse-swizzled global source + swizzled read). 4 waves/block, 16 q-rows/wave,
// 32 kv/tile.
__global__ __launch_bounds__(256, 4) void k_attn(const u16* __restrict__ qr,
                                                 const u16* __restrict__ kr,
                                                 const u16* __restrict__ vt,
                                                 u16* __restrict__ ao) {
  __shared__ __align__(16) u16 kbuf[2][32 * 128];   // [kv][d], swizzled b[6:4]^=(b>>8)&7
  __shared__ __align__(16) u16 vbuf[2][128 * 32];   // [d][kv], swizzled b[5:4]^=(b>>7)&3
  __shared__ __align__(16) u16 plds[4][16 * 40];    // P bounce, rows padded to 40 u16

  const int t = threadIdx.x;
  const int wid = t >> 6, lane = t & 63, lr = lane & 15, lk = lane >> 4;
  const int h = blockIdx.x, bq = blockIdx.y, b = blockIdx.z;
  const int kvh = h >> 2;
  const int Q0 = bq * 64;
  const int q0w = Q0 + wid * 16;
  const u16* qb = qr + (size_t)(b * NH + h) * SEQL * HD;
  const u16* kb = kr + (size_t)(b * NKVH + kvh) * SEQL * HD;
  const u16* vb = vt + (size_t)(b * NKVH + kvh) * HD * SEQL;

  // Q as B-frag: lane holds Q[q0w+lr][kc*32 + lk*8 + j]
  short8 qf[4];
  #pragma unroll
  for (int kc = 0; kc < 4; ++kc)
    qf[kc] = *(const short8*)(qb + (size_t)(q0w + lr) * HD + kc * 32 + lk * 8);

  f32x4 o[8];
  #pragma unroll
  for (int dt = 0; dt < 8; ++dt) o[dt] = f32x4{0.f, 0.f, 0.f, 0.f};
  float mrow = -INFINITY, lrow = 0.f;     // running stats for q = q0w + lr

  int lo = Q0 - (WIN - 1); if (lo < 0) lo = 0;
  const int ktlo = lo >> 5, kthi = (Q0 + 63) >> 5;

  // stage K tile [32][128] u16 (8KB): 512 16B-chunks, 2 per thread
  auto stageK = [&](int bufi, int kv0) {
    #pragma unroll
    for (int i = 0; i < 2; ++i) {
      int c = t + i * 256;
      int bb = c << 4;
      int sb = bb ^ (((bb >> 8) & 7) << 4);   // involution on bits [6:4]
      gld16(kb + (size_t)(kv0 + (sb >> 8)) * HD + ((sb & 255) >> 1),
            &kbuf[bufi][c << 3]);
    }
  };
  // stage V^T tile [128][32] u16 (8KB)
  auto stageV = [&](int bufi, int kv0) {
    #pragma unroll
    for (int i = 0; i < 2; ++i) {
      int c = t + i * 256;
      int bb = c << 4;
      int sb = bb ^ (((bb >> 7) & 3) << 4);   // involution on bits [5:4]
      gld16(vb + (size_t)(sb >> 6) * SEQL + kv0 + ((sb & 63) >> 1),
            &vbuf[bufi][c << 3]);
    }
  };

  stageK(0, ktlo << 5);
  stageV(0, ktlo << 5);
  __syncthreads();

  for (int kt = ktlo; kt <= kthi; ++kt) {
    const int cur = kt & 1;
    if (kt < kthi) { stageK(cur ^ 1, (kt + 1) << 5); stageV(cur ^ 1, (kt + 1) << 5); }
    const int kv0 = kt << 5;
    // wave-uniform skip: does this tile intersect this wave's window?
    if (kv0 + 31 >= q0w - (WIN - 1) && kv0 <= q0w + 15) {
      // QK^T swapped: A = K rows (lr, lr+16), B = Q
      f32x4 sv0 = f32x4{0.f, 0.f, 0.f, 0.f}, sv1 = sv0;
      const u16* lks = kbuf[cur];
      #pragma unroll
      for (int kc = 0; kc < 4; ++kc) {
        int b0 = (lr * 256 + kc * 64 + lk * 16) ^ ((lr & 7) << 4);
        int b1 = ((lr + 16) * 256 + kc * 64 + lk * 16) ^ ((lr & 7) << 4);
        short8 k0 = *(const short8*)(lks + (b0 >> 1));
        short8 k1 = *(const short8*)(lks + (b1 >> 1));
        sv0 = __builtin_amdgcn_mfma_f32_16x16x32_bf16(k0, qf[kc], sv0, 0, 0, 0);
        sv1 = __builtin_amdgcn_mfma_f32_16x16x32_bf16(k1, qf[kc], sv1, 0, 0, 0);
      }
      // lane holds S[kv0 + lk*4 + r (+16)][q = q0w + lr]
      const int qg = q0w + lr;
      float pv[8];
      float tmax = -1e30f;
      #pragma unroll
      for (int r = 0; r < 4; ++r) {
        int kg0 = kv0 + lk * 4 + r, kg1 = kg0 + 16;
        float v0 = softcap_f(sv0[r] * QKSCALE);
        float v1 = softcap_f(sv1[r] * QKSCALE);
        if (!(kg0 <= qg && kg0 > qg - WIN)) v0 = -1e30f;
        if (!(kg1 <= qg && kg1 > qg - WIN)) v1 = -1e30f;
        pv[r] = v0; pv[r + 4] = v1;
        tmax = fmaxf(tmax, fmaxf(v0, v1));
      }
      tmax = fmaxf(tmax, __shfl_xor(tmax, 16));
      tmax = fmaxf(tmax, __shfl_xor(tmax, 32));
      float mnew = fmaxf(mrow, tmax);
      float alpha = __expf(mrow - mnew);     // exp(-inf)=0 handles first tile
      mrow = mnew;
      float rs = 0.f;
      #pragma unroll
      for (int r = 0; r < 8; ++r) {
        pv[r] = (pv[r] > -1e29f) ? __expf(pv[r] - mnew) : 0.f;
        rs += pv[r];
      }
      rs += __shfl_xor(rs, 16); rs += __shfl_xor(rs, 32);
      lrow = lrow * alpha + rs;
      // P -> LDS (q-row lr, kv cols lk*4.. and 16+lk*4..), padded rows kill conflicts
      uint32_t d0 = (uint32_t)f2bf(pv[0]) | ((uint32_t)f2bf(pv[1]) << 16);
      uint32_t d1 = (uint32_t)f2bf(pv[2]) | ((uint32_t)f2bf(pv[3]) << 16);
      uint32_t d2 = (uint32_t)f2bf(pv[4]) | ((uint32_t)f2bf(pv[5]) << 16);
      uint32_t d3 = (uint32_t)f2bf(pv[6]) | ((uint32_t)f2bf(pv[7]) << 16);
      *(uint2*)(plds[wid] + lr * 40 + lk * 4)      = uint2{d0, d1};
      *(uint2*)(plds[wid] + lr * 40 + 16 + lk * 4) = uint2{d2, d3};
      // redistribute alpha to o-layout rows (q = lk*4 + r held by lane lk*4+r)
      float a_o[4];
      #pragma unroll
      for (int r = 0; r < 4; ++r) a_o[r] = __shfl(alpha, lk * 4 + r);
      #pragma unroll
      for (int dt = 0; dt < 8; ++dt)
        #pragma unroll
        for (int r = 0; r < 4; ++r) o[dt][r] *= a_o[r];
      // PV: A = P (a-frag from plds), B = V^T rows from swizzled vbuf
      short8 pf = *(const short8*)(plds[wid] + lr * 40 + lk * 8);
      const u16* lvs = vbuf[cur];
      #pragma unroll
      for (int dt = 0; dt < 8; ++dt) {
        int row = dt * 16 + lr;
        int bb = (row * 64 + lk * 16) ^ (((row >> 1) & 3) << 4);
        o[dt] = __builtin_amdgcn_mfma_f32_16x16x32_bf16(pf, *(const short8*)(lvs + (bb >> 1)), o[dt], 0, 0, 0);
      }
    }
    __syncthreads();
  }

  float rinv = 1.0f / lrow;                 // for q = q0w + lr
  #pragma unroll
  for (int r = 0; r < 4; ++r) {
    float inv = __shfl(rinv, lk * 4 + r);   // to o-layout row q = lk*4 + r
    const int srow = q0w + lk * 4 + r;
    u16* op = ao + (size_t)(b * SEQL + srow) * DM + h * HD;
    #pragma unroll
    for (int dt = 0; dt < 8; ++dt) op[dt * 16 + lr] = f2bf(o[dt][r] * inv);
  }
}

extern "C" void kernel_launch(void* const* d_in, const int* in_sizes, int n_in,
                              void* d_out, int out_size, void* d_ws, size_t ws_size,
                              hipStream_t stream) {
  (void)in_sizes; (void)n_in; (void)out_size; (void)ws_size;
  const float* hs = (const float*)d_in[0];
  const float* wq = (const float*)d_in[1];
  const float* wk = (const float*)d_in[2];
  const float* wv = (const float*)d_in[3];
  const float* wo = (const float*)d_in[4];
  float* out = (float*)d_out;

  u16* ws    = (u16*)d_ws;
  u16* A_bf  = ws;                      //  8,388,608  hs bf16 [4096][2048]
  u16* Wqkv  = A_bf + 8388608;          //  6,291,456  packed [3072][2048]
  u16* Cqkv  = Wqkv + 6291456;          // 12,582,912  [4096][3072]
  u16* q_r   = Cqkv + 12582912;         //  8,388,608  [b][h][s][128]
  u16* k_r   = q_r + 8388608;           //  2,097,152  [b][kvh][s][128]
  u16* vTb   = k_r + 2097152;           //  2,097,152  [b][kvh][128][s]
  float* cosT = (float*)(vTb + 2097152);
  float* sinT = cosT + 131072;
  u16* Wo   = Cqkv;                     // reuse Cqkv after rope/vt consume it
  u16* aout = A_bf;                     // reuse A_bf after QKV gemm

  k_cast<<<8192, 256, 0, stream>>>(hs, A_bf, 2097152);
  k_cast<<<4096, 256, 0, stream>>>(wq, Wqkv, 1048576);
  k_cast<<<1024, 256, 0, stream>>>(wk, Wqkv + 4194304, 262144);
  k_cast<<<1024, 256, 0, stream>>>(wv, Wqkv + 5242880, 262144);
  k_rope_table<<<2048, 64, 0, stream>>>(cosT, sinT);

  k_gemm_bt<u16><<<dim3(NQKV / 128, MR / 128), 256, 0, stream>>>(A_bf, Wqkv, Cqkv, NQKV, DM);

  k_rope_q<<<16384, 256, 0, stream>>>(Cqkv, cosT, sinT, q_r);
  k_rope_k<<<4096, 256, 0, stream>>>(Cqkv, cosT, sinT, k_r);
  k_vt<<<8192, 256, 0, stream>>>(Cqkv, vTb);
  k_cast<<<4096, 256, 0, stream>>>(wo, Wo, 1048576);

  // equal-work dispatch order: x = head (same tile count), y = q-block, z = batch
  k_attn<<<dim3(NH, SEQL / 64, BAT), 256, 0, stream>>>(q_r, k_r, vTb, aout);

  k_gemm_bt<float><<<dim3(DM / 128, MR / 128), 256, 0, stream>>>(aout, Wo, out, DM, DM);
}

// Round 3
// 248.251 us; speedup vs baseline: 1.4225x; 1.0282x over previous
//
#include <hip/hip_runtime.h>
#include <hip/hip_bf16.h>
#include <stdint.h>

// Problem constants
#define DM    2048
#define NH    16
#define NKVH  4
#define HD    128
#define WIN   512
#define SEQL  2048
#define BAT   2
#define MR    (BAT*SEQL)        // 4096 rows
#define NQKV  3072              // 2048 q + 512 k + 512 v
#define QKSCALE 0.08838834764831845f
#define CAP   50.0f

typedef unsigned short u16;
typedef __attribute__((ext_vector_type(8))) short short8;
typedef __attribute__((ext_vector_type(4))) float f32x4;

__device__ __forceinline__ u16 f2bf(float f) {
  union { float f; uint32_t u; } v; v.f = f;
  uint32_t r = v.u + 0x7FFFu + ((v.u >> 16) & 1u);
  return (u16)(r >> 16);
}
__device__ __forceinline__ float bf2f(u16 h) {
  union { uint32_t u; float f; } v; v.u = ((uint32_t)h) << 16; return v.f;
}
__device__ __forceinline__ void gld16(const void* g, void* l) {
  __builtin_amdgcn_global_load_lds((const __attribute__((address_space(1))) void*)g,
                                   (__attribute__((address_space(3))) void*)l,
                                   16, 0, 0);
}
__device__ __forceinline__ float softcap_f(float v) {
  float x = v * (1.0f / CAP);
  x = fminf(fmaxf(x, -15.f), 15.f);
  float e = __expf(2.0f * x);
  return CAP * ((e - 1.0f) / (e + 1.0f));
}

// ---------------- elementwise: fp32 -> bf16 cast ----------------
__global__ void k_cast(const float* __restrict__ src, u16* __restrict__ dst, int n4) {
  int i = blockIdx.x * 256 + threadIdx.x;
  if (i >= n4) return;
  float4 v = ((const float4*)src)[i];
  ushort4 o;
  o.x = f2bf(v.x); o.y = f2bf(v.y); o.z = f2bf(v.z); o.w = f2bf(v.w);
  ((ushort4*)dst)[i] = o;
}

// ---------------- RoPE cos/sin table: [S][64] ----------------
__global__ void k_rope_table(float* __restrict__ c, float* __restrict__ sn) {
  int s = blockIdx.x, i = threadIdx.x;
  float invf = expf(-(float)i * (9.210340371976184f / 64.0f));
  float a = (float)s * invf;
  c[(s << 6) + i]  = cosf(a);
  sn[(s << 6) + i] = sinf(a);
}

// ---------------- GEMM: C[M][N] = A[M][K] * B[N][K]^T, bf16 in, f32 acc ----------------
// 4-slot BK=32 counted-vmcnt pipeline (T3/T4): stage tile t+3 during tile t;
// wait vmcnt(8) (tiles t+1,t+2 in flight) - never drain in main loop.
// T2 swizzle (rule #21): linear gld_lds dest + pre-swizzled global source +
// swizzled ds_read. T5 setprio around MFMA cluster.
template <typename OutT>
__global__ __launch_bounds__(256, 2) void k_gemm_bt(const u16* __restrict__ A,
                                                    const u16* __restrict__ Bm,
                                                    OutT* __restrict__ C,
                                                    int N, int K) {
  __shared__ __align__(16) u16 ldsA[4][128 * 32];   // 8 KB per slot
  __shared__ __align__(16) u16 ldsB[4][128 * 32];
  const int t = threadIdx.x;
  const int bn = blockIdx.x, bm = blockIdx.y;
  const int m0 = bm * 128, n0 = bn * 128;
  const int lane = t & 63, wid = t >> 6;
  const int lr = lane & 15, lk = lane >> 4;
  const int wr = (wid >> 1) * 64, wc = (wid & 1) * 64;
  const int nt = K >> 5;                            // BK = 32

  // stage one K-tile (A+B, 4 gld16/thread) into slot, swizzled source
  auto stage = [&](int slot, int kt) {
    #pragma unroll
    for (int i = 0; i < 2; ++i) {
      const int row = i * 64 + (t >> 2);
      const int sc = (((t & 3) ^ ((row >> 1) & 3)) << 3);   // swizzled src col (u16)
      gld16(A  + (size_t)(m0 + row) * K + kt * 32 + sc, &ldsA[slot][i * 2048 + t * 8]);
      gld16(Bm + (size_t)(n0 + row) * K + kt * 32 + sc, &ldsB[slot][i * 2048 + t * 8]);
    }
  };
  // swizzled LDS byte offset for logical (row, 16B-chunk lk)
  auto swzb = [](int row, int ck) -> int {
    return (row << 6) | ((((ck ^ (row >> 1)) & 3)) << 4);
  };

  stage(0, 0); stage(1, 1); stage(2, 2);            // 12 loads in flight

  f32x4 acc[4][4];
  #pragma unroll
  for (int mi = 0; mi < 4; ++mi)
    #pragma unroll
    for (int ni = 0; ni < 4; ++ni) acc[mi][ni] = f32x4{0.f, 0.f, 0.f, 0.f};

  for (int kt = 0; kt < nt; ++kt) {
    // counted wait: tile kt's 4 loads are older than the (8/4/0) newest
    if (kt < nt - 2)       asm volatile("s_waitcnt vmcnt(8)" ::: "memory");
    else if (kt == nt - 2) asm volatile("s_waitcnt vmcnt(4)" ::: "memory");
    else                   asm volatile("s_waitcnt vmcnt(0)" ::: "memory");
    __builtin_amdgcn_s_barrier();
    asm volatile("" ::: "memory");
    if (kt + 3 < nt) stage((kt + 3) & 3, kt + 3);   // slot freed at barrier end of kt-1

    const u16* la = ldsA[kt & 3];
    const u16* lb = ldsB[kt & 3];
    short8 af[4], bfv[4];
    #pragma unroll
    for (int mi = 0; mi < 4; ++mi)
      af[mi] = *(const short8*)(la + (swzb(wr + mi * 16 + lr, lk) >> 1));
    #pragma unroll
    for (int ni = 0; ni < 4; ++ni)
      bfv[ni] = *(const short8*)(lb + (swzb(wc + ni * 16 + lr, lk) >> 1));
    __builtin_amdgcn_s_setprio(1);
    #pragma unroll
    for (int mi = 0; mi < 4; ++mi)
      #pragma unroll
      for (int ni = 0; ni < 4; ++ni)
        acc[mi][ni] = __builtin_amdgcn_mfma_f32_16x16x32_bf16(af[mi], bfv[ni], acc[mi][ni], 0, 0, 0);
    __builtin_amdgcn_s_setprio(0);
  }

  // epilogue: C/D layout col=lane&15, row=(lane>>4)*4+reg  [m89-verified]
  #pragma unroll
  for (int mi = 0; mi < 4; ++mi) {
    #pragma unroll
    for (int ni = 0; ni < 4; ++ni) {
      const int r0 = m0 + wr + mi * 16 + lk * 4;
      const int c  = n0 + wc + ni * 16 + lr;
      #pragma unroll
      for (int r = 0; r < 4; ++r) {
        float v = acc[mi][ni][r];
        if constexpr (__is_same(OutT, float)) C[(size_t)(r0 + r) * N + c] = v;
        else                                  C[(size_t)(r0 + r) * N + c] = f2bf(v);
      }
    }
  }
}

// ---------------- RoPE on Q ----------------
__global__ void k_rope_q(const u16* __restrict__ C, const float* __restrict__ cosT,
                         const float* __restrict__ sinT, u16* __restrict__ qr) {
  int idx = blockIdx.x * 256 + threadIdx.x;
  int i = idx & 63, hh = (idx >> 6) & 15, m = idx >> 10;
  int s = m & (SEQL - 1), b = m >> 11;
  size_t cb = (size_t)m * NQKV + hh * HD + i;
  float x1 = bf2f(C[cb]), x2 = bf2f(C[cb + 64]);
  float c = cosT[(s << 6) + i], sn = sinT[(s << 6) + i];
  size_t ob = ((size_t)(b * NH + hh) * SEQL + s) * HD + i;
  qr[ob]      = f2bf(x1 * c - x2 * sn);
  qr[ob + 64] = f2bf(x2 * c + x1 * sn);
}

// ---------------- RoPE on K ----------------
__global__ void k_rope_k(const u16* __restrict__ C, const float* __restrict__ cosT,
                         const float* __restrict__ sinT, u16* __restrict__ kr) {
  int idx = blockIdx.x * 256 + threadIdx.x;
  int i = idx & 63, kvh = (idx >> 6) & 3, m = idx >> 8;
  int s = m & (SEQL - 1), b = m >> 11;
  size_t cb = (size_t)m * NQKV + 2048 + kvh * HD + i;
  float x1 = bf2f(C[cb]), x2 = bf2f(C[cb + 64]);
  float c = cosT[(s << 6) + i], sn = sinT[(s << 6) + i];
  size_t ob = ((size_t)(b * NKVH + kvh) * SEQL + s) * HD + i;
  kr[ob]      = f2bf(x1 * c - x2 * sn);
  kr[ob + 64] = f2bf(x2 * c + x1 * sn);
}

// ---------------- V transpose: -> vt[b][kvh][d][s] ----------------
__global__ void k_vt(const u16* __restrict__ C, u16* __restrict__ vt) {
  int idx = blockIdx.x * 256 + threadIdx.x;
  int s = idx & (SEQL - 1);
  int d = (idx >> 11) & 127;
  int kvh = (idx >> 18) & 3;
  int b = idx >> 20;
  int m = b * SEQL + s;
  vt[idx] = C[(size_t)m * NQKV + 2560 + kvh * HD + d];
}

// ---------------- flash attention: window=512, softcap, GQA ----------------
__global__ __launch_bounds__(256, 4) void k_attn(const u16* __restrict__ qr,
                                                 const u16* __restrict__ kr,
                                                 const u16* __restrict__ vt,
                                                 u16* __restrict__ ao) {
  __shared__ __align__(16) u16 kbuf[2][32 * 128];
  __shared__ __align__(16) u16 vbuf[2][128 * 32];
  __shared__ __align__(16) u16 plds[4][16 * 40];

  const int t = threadIdx.x;
  const int wid = t >> 6, lane = t & 63, lr = lane & 15, lk = lane >> 4;
  const int h = blockIdx.x, bq = blockIdx.y, b = blockIdx.z;
  const int kvh = h >> 2;
  const int Q0 = bq * 64;
  const int q0w = Q0 + wid * 16;
  const u16* qb = qr + (size_t)(b * NH + h) * SEQL * HD;
  const u16* kb = kr + (size_t)(b * NKVH + kvh) * SEQL * HD;
  const u16* vb = vt + (size_t)(b * NKVH + kvh) * HD * SEQL;

  short8 qf[4];
  #pragma unroll
  for (int kc = 0; kc < 4; ++kc)
    qf[kc] = *(const short8*)(qb + (size_t)(q0w + lr) * HD + kc * 32 + lk * 8);

  f32x4 o[8];
  #pragma unroll
  for (int dt = 0; dt < 8; ++dt) o[dt] = f32x4{0.f, 0.f, 0.f, 0.f};
  float mrow = -INFINITY, lrow = 0.f;

  int lo = Q0 - (WIN - 1); if (lo < 0) lo = 0;
  const int ktlo = lo >> 5, kthi = (Q0 + 63) >> 5;

  auto stageK = [&](int bufi, int kv0) {
    #pragma unroll
    for (int i = 0; i < 2; ++i) {
      int c = t + i * 256;
      int bb = c << 4;
      int sb = bb ^ (((bb >> 8) & 7) << 4);
      gld16(kb + (size_t)(kv0 + (sb >> 8)) * HD + ((sb & 255) >> 1),
            &kbuf[bufi][c << 3]);
    }
  };
  auto stageV = [&](int bufi, int kv0) {
    #pragma unroll
    for (int i = 0; i < 2; ++i) {
      int c = t + i * 256;
      int bb = c << 4;
      int sb = bb ^ (((bb >> 7) & 3) << 4);
      gld16(vb + (size_t)(sb >> 6) * SEQL + kv0 + ((sb & 63) >> 1),
            &vbuf[bufi][c << 3]);
    }
  };

  stageK(0, ktlo << 5);
  stageV(0, ktlo << 5);
  __syncthreads();

  for (int kt = ktlo; kt <= kthi; ++kt) {
    const int cur = kt & 1;
    if (kt < kthi) { stageK(cur ^ 1, (kt + 1) << 5); stageV(cur ^ 1, (kt + 1) << 5); }
    const int kv0 = kt << 5;
    if (kv0 + 31 >= q0w - (WIN - 1) && kv0 <= q0w + 15) {
      f32x4 sv0 = f32x4{0.f, 0.f, 0.f, 0.f}, sv1 = sv0;
      const u16* lks = kbuf[cur];
      #pragma unroll
      for (int kc = 0; kc < 4; ++kc) {
        int b0 = (lr * 256 + kc * 64 + lk * 16) ^ ((lr & 7) << 4);
        int b1 = ((lr + 16) * 256 + kc * 64 + lk * 16) ^ ((lr & 7) << 4);
        short8 k0 = *(const short8*)(lks + (b0 >> 1));
        short8 k1 = *(const short8*)(lks + (b1 >> 1));
        sv0 = __builtin_amdgcn_mfma_f32_16x16x32_bf16(k0, qf[kc], sv0, 0, 0, 0);
        sv1 = __builtin_amdgcn_mfma_f32_16x16x32_bf16(k1, qf[kc], sv1, 0, 0, 0);
      }
      const int qg = q0w + lr;
      float pv[8];
      float tmax = -1e30f;
      #pragma unroll
      for (int r = 0; r < 4; ++r) {
        int kg0 = kv0 + lk * 4 + r, kg1 = kg0 + 16;
        float v0 = softcap_f(sv0[r] * QKSCALE);
        float v1 = softcap_f(sv1[r] * QKSCALE);
        if (!(kg0 <= qg && kg0 > qg - WIN)) v0 = -1e30f;
        if (!(kg1 <= qg && kg1 > qg - WIN)) v1 = -1e30f;
        pv[r] = v0; pv[r + 4] = v1;
        tmax = fmaxf(tmax, fmaxf(v0, v1));
      }
      tmax = fmaxf(tmax, __shfl_xor(tmax, 16));
      tmax = fmaxf(tmax, __shfl_xor(tmax, 32));
      float mnew = fmaxf(mrow, tmax);
      float alpha = __expf(mrow - mnew);
      mrow = mnew;
      float rs = 0.f;
      #pragma unroll
      for (int r = 0; r < 8; ++r) {
        pv[r] = (pv[r] > -1e29f) ? __expf(pv[r] - mnew) : 0.f;
        rs += pv[r];
      }
      rs += __shfl_xor(rs, 16); rs += __shfl_xor(rs, 32);
      lrow = lrow * alpha + rs;
      uint32_t d0 = (uint32_t)f2bf(pv[0]) | ((uint32_t)f2bf(pv[1]) << 16);
      uint32_t d1 = (uint32_t)f2bf(pv[2]) | ((uint32_t)f2bf(pv[3]) << 16);
      uint32_t d2 = (uint32_t)f2bf(pv[4]) | ((uint32_t)f2bf(pv[5]) << 16);
      uint32_t d3 = (uint32_t)f2bf(pv[6]) | ((uint32_t)f2bf(pv[7]) << 16);
      *(uint2*)(plds[wid] + lr * 40 + lk * 4)      = uint2{d0, d1};
      *(uint2*)(plds[wid] + lr * 40 + 16 + lk * 4) = uint2{d2, d3};
      float a_o[4];
      #pragma unroll
      for (int r = 0; r < 4; ++r) a_o[r] = __shfl(alpha, lk * 4 + r);
      #pragma unroll
      for (int dt = 0; dt < 8; ++dt)
        #pragma unroll
        for (int r = 0; r < 4; ++r) o[dt][r] *= a_o[r];
      short8 pf = *(const short8*)(plds[wid] + lr * 40 + lk * 8);
      const u16* lvs = vbuf[cur];
      #pragma unroll
      for (int dt = 0; dt < 8; ++dt) {
        int row = dt * 16 + lr;
        int bb = (row * 64 + lk * 16) ^ (((row >> 1) & 3) << 4);
        o[dt] = __builtin_amdgcn_mfma_f32_16x16x32_bf16(pf, *(const short8*)(lvs + (bb >> 1)), o[dt], 0, 0, 0);
      }
    }
    __syncthreads();
  }

  float rinv = 1.0f / lrow;
  #pragma unroll
  for (int r = 0; r < 4; ++r) {
    float inv = __shfl(rinv, lk * 4 + r);
    const int srow = q0w + lk * 4 + r;
    u16* op = ao + (size_t)(b * SEQL + srow) * DM + h * HD;
    #pragma unroll
    for (int dt = 0; dt < 8; ++dt) op[dt * 16 + lr] = f2bf(o[dt][r] * inv);
  }
}

extern "C" void kernel_launch(void* const* d_in, const int* in_sizes, int n_in,
                              void* d_out, int out_size, void* d_ws, size_t ws_size,
                              hipStream_t stream) {
  (void)in_sizes; (void)n_in; (void)out_size; (void)ws_size;
  const float* hs = (const float*)d_in[0];
  const float* wq = (const float*)d_in[1];
  const float* wk = (const float*)d_in[2];
  const float* wv = (const float*)d_in[3];
  const float* wo = (const float*)d_in[4];
  float* out = (float*)d_out;

  u16* ws    = (u16*)d_ws;
  u16* A_bf  = ws;                      //  8,388,608  hs bf16 [4096][2048]
  u16* Wqkv  = A_bf + 8388608;          //  6,291,456  packed [3072][2048]
  u16* Cqkv  = Wqkv + 6291456;          // 12,582,912  [4096][3072]
  u16* q_r   = Cqkv + 12582912;         //  8,388,608  [b][h][s][128]
  u16* k_r   = q_r + 8388608;           //  2,097,152  [b][kvh][s][128]
  u16* vTb   = k_r + 2097152;           //  2,097,152  [b][kvh][128][s]
  float* cosT = (float*)(vTb + 2097152);
  float* sinT = cosT + 131072;
  u16* Wo   = Cqkv;                     // reuse Cqkv after rope/vt consume it
  u16* aout = A_bf;                     // reuse A_bf after QKV gemm

  k_cast<<<8192, 256, 0, stream>>>(hs, A_bf, 2097152);
  k_cast<<<4096, 256, 0, stream>>>(wq, Wqkv, 1048576);
  k_cast<<<1024, 256, 0, stream>>>(wk, Wqkv + 4194304, 262144);
  k_cast<<<1024, 256, 0, stream>>>(wv, Wqkv + 5242880, 262144);
  k_rope_table<<<2048, 64, 0, stream>>>(cosT, sinT);

  k_gemm_bt<u16><<<dim3(NQKV / 128, MR / 128), 256, 0, stream>>>(A_bf, Wqkv, Cqkv, NQKV, DM);

  k_rope_q<<<16384, 256, 0, stream>>>(Cqkv, cosT, sinT, q_r);
  k_rope_k<<<4096, 256, 0, stream>>>(Cqkv, cosT, sinT, k_r);
  k_vt<<<8192, 256, 0, stream>>>(Cqkv, vTb);
  k_cast<<<4096, 256, 0, stream>>>(wo, Wo, 1048576);

  k_attn<<<dim3(NH, SEQL / 64, BAT), 256, 0, stream>>>(q_r, k_r, vTb, aout);

  k_gemm_bt<float><<<dim3(DM / 128, MR / 128), 256, 0, stream>>>(aout, Wo, out, DM, DM);
}

// Round 4
// 216.148 us; speedup vs baseline: 1.6338x; 1.1485x over previous
//
#include <hip/hip_runtime.h>
#include <hip/hip_bf16.h>
#include <stdint.h>

// Problem constants
#define DM    2048
#define NH    16
#define NKVH  4
#define HD    128
#define WIN   512
#define SEQL  2048
#define BAT   2
#define MR    (BAT*SEQL)        // 4096 rows
#define NQKV  3072              // 2048 q + 512 k + 512 v
#define QKSCALE 0.08838834764831845f
#define CAP   50.0f

typedef unsigned short u16;
typedef __attribute__((ext_vector_type(8))) short short8;
typedef __attribute__((ext_vector_type(4))) float f32x4;

__device__ __forceinline__ u16 f2bf(float f) {
  union { float f; uint32_t u; } v; v.f = f;
  uint32_t r = v.u + 0x7FFFu + ((v.u >> 16) & 1u);
  return (u16)(r >> 16);
}
__device__ __forceinline__ float bf2f(u16 h) {
  union { uint32_t u; float f; } v; v.u = ((uint32_t)h) << 16; return v.f;
}
__device__ __forceinline__ void gld16(const void* g, void* l) {
  __builtin_amdgcn_global_load_lds((const __attribute__((address_space(1))) void*)g,
                                   (__attribute__((address_space(3))) void*)l,
                                   16, 0, 0);
}
__device__ __forceinline__ float softcap_f(float v) {
  float x = v * (1.0f / CAP);
  x = fminf(fmaxf(x, -15.f), 15.f);
  float e = __expf(2.0f * x);
  return CAP * ((e - 1.0f) / (e + 1.0f));
}

// ---------------- elementwise: fp32 -> bf16 cast ----------------
__global__ void k_cast(const float* __restrict__ src, u16* __restrict__ dst, int n4) {
  int i = blockIdx.x * 256 + threadIdx.x;
  if (i >= n4) return;
  float4 v = ((const float4*)src)[i];
  ushort4 o;
  o.x = f2bf(v.x); o.y = f2bf(v.y); o.z = f2bf(v.z); o.w = f2bf(v.w);
  ((ushort4*)dst)[i] = o;
}

// ---------------- RoPE cos/sin table: [S][64] ----------------
__global__ void k_rope_table(float* __restrict__ c, float* __restrict__ sn) {
  int s = blockIdx.x, i = threadIdx.x;
  float invf = expf(-(float)i * (9.210340371976184f / 64.0f));
  float a = (float)s * invf;
  c[(s << 6) + i]  = cosf(a);
  sn[(s << 6) + i] = sinf(a);
}

// ---------------- GEMM: C[M][N] = A[M][K] * B[N][K]^T, bf16 in, f32 acc ----------------
// m97 structure: 128x128 tile, BK=64, SINGLE 32KB LDS buffer, drain per tile.
// Occupancy is the lever (m114): 32KB LDS + launch_bounds(256,3) -> 3 blocks/CU,
// inter-block overlap hides the drain. T2 swizzle (ck ^= row&7 over 8 chunks)
// keeps ds_read conflict-free. T1 bijective XCD swizzle for A-panel L2 locality.
template <typename OutT>
__global__ __launch_bounds__(256, 3) void k_gemm_bt(const u16* __restrict__ A,
                                                    const u16* __restrict__ Bm,
                                                    OutT* __restrict__ C,
                                                    int N, int K) {
  __shared__ __align__(16) u16 ldsA[128 * 64];    // 16 KB
  __shared__ __align__(16) u16 ldsB[128 * 64];    // 16 KB
  const int t = threadIdx.x;

  // T1: bijective XCD swizzle (nwg % 8 == 0 for both call sites)
  const int nwg  = gridDim.x * gridDim.y;
  const int flat = blockIdx.y * gridDim.x + blockIdx.x;
  const int cpx  = nwg >> 3;
  const int swz  = (flat & 7) * cpx + (flat >> 3);
  const int bn = swz % gridDim.x, bm = swz / gridDim.x;

  const int m0 = bm * 128, n0 = bn * 128;
  const int lane = t & 63, wid = t >> 6;
  const int lr = lane & 15, lk = lane >> 4;
  const int wr = (wid >> 1) * 64, wc = (wid & 1) * 64;
  const int nt = K >> 6;                          // BK = 64

  // staging: thread t covers rows {t>>3 + 32i}, chunk t&7 (16B chunks, 8/row).
  // source col pre-swizzled (ck ^ row&7) so linear LDS + swizzled read match.
  const int srow = t >> 3;
  const int scol = (((t & 7) ^ (srow & 7)) << 3);   // u16 offset, i-invariant

  f32x4 acc[4][4];
  #pragma unroll
  for (int mi = 0; mi < 4; ++mi)
    #pragma unroll
    for (int ni = 0; ni < 4; ++ni) acc[mi][ni] = f32x4{0.f, 0.f, 0.f, 0.f};

  for (int kt = 0; kt < nt; ++kt) {
    { // stage tile kt: 8 gld16/thread (4 A + 4 B)
      const u16* a0 = A  + (size_t)(m0 + srow) * K + kt * 64 + scol;
      const u16* b0 = Bm + (size_t)(n0 + srow) * K + kt * 64 + scol;
      #pragma unroll
      for (int i = 0; i < 4; ++i) {
        gld16(a0 + (size_t)(i * 32) * K, &ldsA[i * 2048 + t * 8]);
        gld16(b0 + (size_t)(i * 32) * K, &ldsB[i * 2048 + t * 8]);
      }
    }
    __syncthreads();              // drains vmcnt -> staged data visible
    #pragma unroll
    for (int ks = 0; ks < 2; ++ks) {
      const int c = ks * 4 + lk;  // logical 16B chunk 0..7
      short8 af[4], bfv[4];
      #pragma unroll
      for (int mi = 0; mi < 4; ++mi) {
        const int ra = wr + mi * 16 + lr;
        af[mi] = *(const short8*)(ldsA + ra * 64 + ((c ^ (ra & 7)) << 3));
      }
      #pragma unroll
      for (int ni = 0; ni < 4; ++ni) {
        const int rb = wc + ni * 16 + lr;
        bfv[ni] = *(const short8*)(ldsB + rb * 64 + ((c ^ (rb & 7)) << 3));
      }
      #pragma unroll
      for (int mi = 0; mi < 4; ++mi)
        #pragma unroll
        for (int ni = 0; ni < 4; ++ni)
          acc[mi][ni] = __builtin_amdgcn_mfma_f32_16x16x32_bf16(af[mi], bfv[ni], acc[mi][ni], 0, 0, 0);
    }
    if (kt + 1 < nt) __syncthreads();   // protect buffer before next stage
  }

  // epilogue: C/D layout col=lane&15, row=(lane>>4)*4+reg  [m89-verified]
  #pragma unroll
  for (int mi = 0; mi < 4; ++mi) {
    #pragma unroll
    for (int ni = 0; ni < 4; ++ni) {
      const int r0 = m0 + wr + mi * 16 + lk * 4;
      const int c  = n0 + wc + ni * 16 + lr;
      #pragma unroll
      for (int r = 0; r < 4; ++r) {
        float v = acc[mi][ni][r];
        if constexpr (__is_same(OutT, float)) C[(size_t)(r0 + r) * N + c] = v;
        else                                  C[(size_t)(r0 + r) * N + c] = f2bf(v);
      }
    }
  }
}

// ---------------- RoPE on Q ----------------
__global__ void k_rope_q(const u16* __restrict__ C, const float* __restrict__ cosT,
                         const float* __restrict__ sinT, u16* __restrict__ qr) {
  int idx = blockIdx.x * 256 + threadIdx.x;
  int i = idx & 63, hh = (idx >> 6) & 15, m = idx >> 10;
  int s = m & (SEQL - 1), b = m >> 11;
  size_t cb = (size_t)m * NQKV + hh * HD + i;
  float x1 = bf2f(C[cb]), x2 = bf2f(C[cb + 64]);
  float c = cosT[(s << 6) + i], sn = sinT[(s << 6) + i];
  size_t ob = ((size_t)(b * NH + hh) * SEQL + s) * HD + i;
  qr[ob]      = f2bf(x1 * c - x2 * sn);
  qr[ob + 64] = f2bf(x2 * c + x1 * sn);
}

// ---------------- RoPE on K ----------------
__global__ void k_rope_k(const u16* __restrict__ C, const float* __restrict__ cosT,
                         const float* __restrict__ sinT, u16* __restrict__ kr) {
  int idx = blockIdx.x * 256 + threadIdx.x;
  int i = idx & 63, kvh = (idx >> 6) & 3, m = idx >> 8;
  int s = m & (SEQL - 1), b = m >> 11;
  size_t cb = (size_t)m * NQKV + 2048 + kvh * HD + i;
  float x1 = bf2f(C[cb]), x2 = bf2f(C[cb + 64]);
  float c = cosT[(s << 6) + i], sn = sinT[(s << 6) + i];
  size_t ob = ((size_t)(b * NKVH + kvh) * SEQL + s) * HD + i;
  kr[ob]      = f2bf(x1 * c - x2 * sn);
  kr[ob + 64] = f2bf(x2 * c + x1 * sn);
}

// ---------------- V transpose: -> vt[b][kvh][d][s] ----------------
__global__ void k_vt(const u16* __restrict__ C, u16* __restrict__ vt) {
  int idx = blockIdx.x * 256 + threadIdx.x;
  int s = idx & (SEQL - 1);
  int d = (idx >> 11) & 127;
  int kvh = (idx >> 18) & 3;
  int b = idx >> 20;
  int m = b * SEQL + s;
  vt[idx] = C[(size_t)m * NQKV + 2560 + kvh * HD + d];
}

// ---------------- flash attention: window=512, softcap, GQA ----------------
__global__ __launch_bounds__(256, 4) void k_attn(const u16* __restrict__ qr,
                                                 const u16* __restrict__ kr,
                                                 const u16* __restrict__ vt,
                                                 u16* __restrict__ ao) {
  __shared__ __align__(16) u16 kbuf[2][32 * 128];
  __shared__ __align__(16) u16 vbuf[2][128 * 32];
  __shared__ __align__(16) u16 plds[4][16 * 40];

  const int t = threadIdx.x;
  const int wid = t >> 6, lane = t & 63, lr = lane & 15, lk = lane >> 4;
  const int h = blockIdx.x, bq = blockIdx.y, b = blockIdx.z;
  const int kvh = h >> 2;
  const int Q0 = bq * 64;
  const int q0w = Q0 + wid * 16;
  const u16* qb = qr + (size_t)(b * NH + h) * SEQL * HD;
  const u16* kb = kr + (size_t)(b * NKVH + kvh) * SEQL * HD;
  const u16* vb = vt + (size_t)(b * NKVH + kvh) * HD * SEQL;

  short8 qf[4];
  #pragma unroll
  for (int kc = 0; kc < 4; ++kc)
    qf[kc] = *(const short8*)(qb + (size_t)(q0w + lr) * HD + kc * 32 + lk * 8);

  f32x4 o[8];
  #pragma unroll
  for (int dt = 0; dt < 8; ++dt) o[dt] = f32x4{0.f, 0.f, 0.f, 0.f};
  float mrow = -INFINITY, lrow = 0.f;

  int lo = Q0 - (WIN - 1); if (lo < 0) lo = 0;
  const int ktlo = lo >> 5, kthi = (Q0 + 63) >> 5;

  auto stageK = [&](int bufi, int kv0) {
    #pragma unroll
    for (int i = 0; i < 2; ++i) {
      int c = t + i * 256;
      int bb = c << 4;
      int sb = bb ^ (((bb >> 8) & 7) << 4);
      gld16(kb + (size_t)(kv0 + (sb >> 8)) * HD + ((sb & 255) >> 1),
            &kbuf[bufi][c << 3]);
    }
  };
  auto stageV = [&](int bufi, int kv0) {
    #pragma unroll
    for (int i = 0; i < 2; ++i) {
      int c = t + i * 256;
      int bb = c << 4;
      int sb = bb ^ (((bb >> 7) & 3) << 4);
      gld16(vb + (size_t)(sb >> 6) * SEQL + kv0 + ((sb & 63) >> 1),
            &vbuf[bufi][c << 3]);
    }
  };

  stageK(0, ktlo << 5);
  stageV(0, ktlo << 5);
  __syncthreads();

  for (int kt = ktlo; kt <= kthi; ++kt) {
    const int cur = kt & 1;
    if (kt < kthi) { stageK(cur ^ 1, (kt + 1) << 5); stageV(cur ^ 1, (kt + 1) << 5); }
    const int kv0 = kt << 5;
    if (kv0 + 31 >= q0w - (WIN - 1) && kv0 <= q0w + 15) {
      f32x4 sv0 = f32x4{0.f, 0.f, 0.f, 0.f}, sv1 = sv0;
      const u16* lks = kbuf[cur];
      #pragma unroll
      for (int kc = 0; kc < 4; ++kc) {
        int b0 = (lr * 256 + kc * 64 + lk * 16) ^ ((lr & 7) << 4);
        int b1 = ((lr + 16) * 256 + kc * 64 + lk * 16) ^ ((lr & 7) << 4);
        short8 k0 = *(const short8*)(lks + (b0 >> 1));
        short8 k1 = *(const short8*)(lks + (b1 >> 1));
        sv0 = __builtin_amdgcn_mfma_f32_16x16x32_bf16(k0, qf[kc], sv0, 0, 0, 0);
        sv1 = __builtin_amdgcn_mfma_f32_16x16x32_bf16(k1, qf[kc], sv1, 0, 0, 0);
      }
      const int qg = q0w + lr;
      float pv[8];
      float tmax = -1e30f;
      #pragma unroll
      for (int r = 0; r < 4; ++r) {
        int kg0 = kv0 + lk * 4 + r, kg1 = kg0 + 16;
        float v0 = softcap_f(sv0[r] * QKSCALE);
        float v1 = softcap_f(sv1[r] * QKSCALE);
        if (!(kg0 <= qg && kg0 > qg - WIN)) v0 = -1e30f;
        if (!(kg1 <= qg && kg1 > qg - WIN)) v1 = -1e30f;
        pv[r] = v0; pv[r + 4] = v1;
        tmax = fmaxf(tmax, fmaxf(v0, v1));
      }
      tmax = fmaxf(tmax, __shfl_xor(tmax, 16));
      tmax = fmaxf(tmax, __shfl_xor(tmax, 32));
      float mnew = fmaxf(mrow, tmax);
      float alpha = __expf(mrow - mnew);
      mrow = mnew;
      float rs = 0.f;
      #pragma unroll
      for (int r = 0; r < 8; ++r) {
        pv[r] = (pv[r] > -1e29f) ? __expf(pv[r] - mnew) : 0.f;
        rs += pv[r];
      }
      rs += __shfl_xor(rs, 16); rs += __shfl_xor(rs, 32);
      lrow = lrow * alpha + rs;
      uint32_t d0 = (uint32_t)f2bf(pv[0]) | ((uint32_t)f2bf(pv[1]) << 16);
      uint32_t d1 = (uint32_t)f2bf(pv[2]) | ((uint32_t)f2bf(pv[3]) << 16);
      uint32_t d2 = (uint32_t)f2bf(pv[4]) | ((uint32_t)f2bf(pv[5]) << 16);
      uint32_t d3 = (uint32_t)f2bf(pv[6]) | ((uint32_t)f2bf(pv[7]) << 16);
      *(uint2*)(plds[wid] + lr * 40 + lk * 4)      = uint2{d0, d1};
      *(uint2*)(plds[wid] + lr * 40 + 16 + lk * 4) = uint2{d2, d3};
      float a_o[4];
      #pragma unroll
      for (int r = 0; r < 4; ++r) a_o[r] = __shfl(alpha, lk * 4 + r);
      #pragma unroll
      for (int dt = 0; dt < 8; ++dt)
        #pragma unroll
        for (int r = 0; r < 4; ++r) o[dt][r] *= a_o[r];
      short8 pf = *(const short8*)(plds[wid] + lr * 40 + lk * 8);
      const u16* lvs = vbuf[cur];
      #pragma unroll
      for (int dt = 0; dt < 8; ++dt) {
        int row = dt * 16 + lr;
        int bb = (row * 64 + lk * 16) ^ (((row >> 1) & 3) << 4);
        o[dt] = __builtin_amdgcn_mfma_f32_16x16x32_bf16(pf, *(const short8*)(lvs + (bb >> 1)), o[dt], 0, 0, 0);
      }
    }
    __syncthreads();
  }

  float rinv = 1.0f / lrow;
  #pragma unroll
  for (int r = 0; r < 4; ++r) {
    float inv = __shfl(rinv, lk * 4 + r);
    const int srow = q0w + lk * 4 + r;
    u16* op = ao + (size_t)(b * SEQL + srow) * DM + h * HD;
    #pragma unroll
    for (int dt = 0; dt < 8; ++dt) op[dt * 16 + lr] = f2bf(o[dt][r] * inv);
  }
}

extern "C" void kernel_launch(void* const* d_in, const int* in_sizes, int n_in,
                              void* d_out, int out_size, void* d_ws, size_t ws_size,
                              hipStream_t stream) {
  (void)in_sizes; (void)n_in; (void)out_size; (void)ws_size;
  const float* hs = (const float*)d_in[0];
  const float* wq = (const float*)d_in[1];
  const float* wk = (const float*)d_in[2];
  const float* wv = (const float*)d_in[3];
  const float* wo = (const float*)d_in[4];
  float* out = (float*)d_out;

  u16* ws    = (u16*)d_ws;
  u16* A_bf  = ws;                      //  8,388,608  hs bf16 [4096][2048]
  u16* Wqkv  = A_bf + 8388608;          //  6,291,456  packed [3072][2048]
  u16* Cqkv  = Wqkv + 6291456;          // 12,582,912  [4096][3072]
  u16* q_r   = Cqkv + 12582912;         //  8,388,608  [b][h][s][128]
  u16* k_r   = q_r + 8388608;           //  2,097,152  [b][kvh][s][128]
  u16* vTb   = k_r + 2097152;           //  2,097,152  [b][kvh][128][s]
  float* cosT = (float*)(vTb + 2097152);
  float* sinT = cosT + 131072;
  u16* Wo   = Cqkv;                     // reuse Cqkv after rope/vt consume it
  u16* aout = A_bf;                     // reuse A_bf after QKV gemm

  k_cast<<<8192, 256, 0, stream>>>(hs, A_bf, 2097152);
  k_cast<<<4096, 256, 0, stream>>>(wq, Wqkv, 1048576);
  k_cast<<<1024, 256, 0, stream>>>(wk, Wqkv + 4194304, 262144);
  k_cast<<<1024, 256, 0, stream>>>(wv, Wqkv + 5242880, 262144);
  k_rope_table<<<2048, 64, 0, stream>>>(cosT, sinT);

  k_gemm_bt<u16><<<dim3(NQKV / 128, MR / 128), 256, 0, stream>>>(A_bf, Wqkv, Cqkv, NQKV, DM);

  k_rope_q<<<16384, 256, 0, stream>>>(Cqkv, cosT, sinT, q_r);
  k_rope_k<<<4096, 256, 0, stream>>>(Cqkv, cosT, sinT, k_r);
  k_vt<<<8192, 256, 0, stream>>>(Cqkv, vTb);
  k_cast<<<4096, 256, 0, stream>>>(wo, Wo, 1048576);

  k_attn<<<dim3(NH, SEQL / 64, BAT), 256, 0, stream>>>(q_r, k_r, vTb, aout);

  k_gemm_bt<float><<<dim3(DM / 128, MR / 128), 256, 0, stream>>>(aout, Wo, out, DM, DM);
}

// Round 5
// 201.344 us; speedup vs baseline: 1.7539x; 1.0735x over previous
//
#include <hip/hip_runtime.h>
#include <hip/hip_bf16.h>
#include <stdint.h>

// Problem constants
#define DM    2048
#define NH    16
#define NKVH  4
#define HD    128
#define WIN   512
#define SEQL  2048
#define BAT   2
#define MR    (BAT*SEQL)        // 4096 rows
#define NQKV  3072              // 2048 q + 512 k + 512 v
#define QKSCALE 0.08838834764831845f
#define CAP   50.0f

typedef unsigned short u16;
typedef __attribute__((ext_vector_type(8))) short short8;
typedef __attribute__((ext_vector_type(4))) float f32x4;

__device__ __forceinline__ u16 f2bf(float f) {
  union { float f; uint32_t u; } v; v.f = f;
  uint32_t r = v.u + 0x7FFFu + ((v.u >> 16) & 1u);
  return (u16)(r >> 16);
}
__device__ __forceinline__ float bf2f(u16 h) {
  union { uint32_t u; float f; } v; v.u = ((uint32_t)h) << 16; return v.f;
}
__device__ __forceinline__ void gld16(const void* g, void* l) {
  __builtin_amdgcn_global_load_lds((const __attribute__((address_space(1))) void*)g,
                                   (__attribute__((address_space(3))) void*)l,
                                   16, 0, 0);
}
__device__ __forceinline__ float softcap_f(float v) {
  float x = v * (1.0f / CAP);
  x = fminf(fmaxf(x, -15.f), 15.f);
  float e = __expf(2.0f * x);
  return CAP * ((e - 1.0f) / (e + 1.0f));
}

// ---------------- elementwise: fp32 -> bf16 cast ----------------
__global__ void k_cast(const float* __restrict__ src, u16* __restrict__ dst, int n4) {
  int i = blockIdx.x * 256 + threadIdx.x;
  if (i >= n4) return;
  float4 v = ((const float4*)src)[i];
  ushort4 o;
  o.x = f2bf(v.x); o.y = f2bf(v.y); o.z = f2bf(v.z); o.w = f2bf(v.w);
  ((ushort4*)dst)[i] = o;
}

// ---------------- RoPE cos/sin table: [S][64] ----------------
__global__ void k_rope_table(float* __restrict__ c, float* __restrict__ sn) {
  int s = blockIdx.x, i = threadIdx.x;
  float invf = expf(-(float)i * (9.210340371976184f / 64.0f));
  float a = (float)s * invf;
  c[(s << 6) + i]  = cosf(a);
  sn[(s << 6) + i] = sinf(a);
}

// ---------------- GEMM: C[M][N] = A[M][K] * B[N][K]^T, bf16 in, f32 acc ----------------
// m97 structure (unchanged from R4: 940 TF, at structure ceiling)
template <typename OutT>
__global__ __launch_bounds__(256, 3) void k_gemm_bt(const u16* __restrict__ A,
                                                    const u16* __restrict__ Bm,
                                                    OutT* __restrict__ C,
                                                    int N, int K) {
  __shared__ __align__(16) u16 ldsA[128 * 64];    // 16 KB
  __shared__ __align__(16) u16 ldsB[128 * 64];    // 16 KB
  const int t = threadIdx.x;

  const int nwg  = gridDim.x * gridDim.y;
  const int flat = blockIdx.y * gridDim.x + blockIdx.x;
  const int cpx  = nwg >> 3;
  const int swz  = (flat & 7) * cpx + (flat >> 3);
  const int bn = swz % gridDim.x, bm = swz / gridDim.x;

  const int m0 = bm * 128, n0 = bn * 128;
  const int lane = t & 63, wid = t >> 6;
  const int lr = lane & 15, lk = lane >> 4;
  const int wr = (wid >> 1) * 64, wc = (wid & 1) * 64;
  const int nt = K >> 6;

  const int srow = t >> 3;
  const int scol = (((t & 7) ^ (srow & 7)) << 3);

  f32x4 acc[4][4];
  #pragma unroll
  for (int mi = 0; mi < 4; ++mi)
    #pragma unroll
    for (int ni = 0; ni < 4; ++ni) acc[mi][ni] = f32x4{0.f, 0.f, 0.f, 0.f};

  for (int kt = 0; kt < nt; ++kt) {
    {
      const u16* a0 = A  + (size_t)(m0 + srow) * K + kt * 64 + scol;
      const u16* b0 = Bm + (size_t)(n0 + srow) * K + kt * 64 + scol;
      #pragma unroll
      for (int i = 0; i < 4; ++i) {
        gld16(a0 + (size_t)(i * 32) * K, &ldsA[i * 2048 + t * 8]);
        gld16(b0 + (size_t)(i * 32) * K, &ldsB[i * 2048 + t * 8]);
      }
    }
    __syncthreads();
    #pragma unroll
    for (int ks = 0; ks < 2; ++ks) {
      const int c = ks * 4 + lk;
      short8 af[4], bfv[4];
      #pragma unroll
      for (int mi = 0; mi < 4; ++mi) {
        const int ra = wr + mi * 16 + lr;
        af[mi] = *(const short8*)(ldsA + ra * 64 + ((c ^ (ra & 7)) << 3));
      }
      #pragma unroll
      for (int ni = 0; ni < 4; ++ni) {
        const int rb = wc + ni * 16 + lr;
        bfv[ni] = *(const short8*)(ldsB + rb * 64 + ((c ^ (rb & 7)) << 3));
      }
      #pragma unroll
      for (int mi = 0; mi < 4; ++mi)
        #pragma unroll
        for (int ni = 0; ni < 4; ++ni)
          acc[mi][ni] = __builtin_amdgcn_mfma_f32_16x16x32_bf16(af[mi], bfv[ni], acc[mi][ni], 0, 0, 0);
    }
    if (kt + 1 < nt) __syncthreads();
  }

  #pragma unroll
  for (int mi = 0; mi < 4; ++mi) {
    #pragma unroll
    for (int ni = 0; ni < 4; ++ni) {
      const int r0 = m0 + wr + mi * 16 + lk * 4;
      const int c  = n0 + wc + ni * 16 + lr;
      #pragma unroll
      for (int r = 0; r < 4; ++r) {
        float v = acc[mi][ni][r];
        if constexpr (__is_same(OutT, float)) C[(size_t)(r0 + r) * N + c] = v;
        else                                  C[(size_t)(r0 + r) * N + c] = f2bf(v);
      }
    }
  }
}

// ---------------- RoPE on Q ----------------
__global__ void k_rope_q(const u16* __restrict__ C, const float* __restrict__ cosT,
                         const float* __restrict__ sinT, u16* __restrict__ qr) {
  int idx = blockIdx.x * 256 + threadIdx.x;
  int i = idx & 63, hh = (idx >> 6) & 15, m = idx >> 10;
  int s = m & (SEQL - 1), b = m >> 11;
  size_t cb = (size_t)m * NQKV + hh * HD + i;
  float x1 = bf2f(C[cb]), x2 = bf2f(C[cb + 64]);
  float c = cosT[(s << 6) + i], sn = sinT[(s << 6) + i];
  size_t ob = ((size_t)(b * NH + hh) * SEQL + s) * HD + i;
  qr[ob]      = f2bf(x1 * c - x2 * sn);
  qr[ob + 64] = f2bf(x2 * c + x1 * sn);
}

// ---------------- RoPE on K ----------------
__global__ void k_rope_k(const u16* __restrict__ C, const float* __restrict__ cosT,
                         const float* __restrict__ sinT, u16* __restrict__ kr) {
  int idx = blockIdx.x * 256 + threadIdx.x;
  int i = idx & 63, kvh = (idx >> 6) & 3, m = idx >> 8;
  int s = m & (SEQL - 1), b = m >> 11;
  size_t cb = (size_t)m * NQKV + 2048 + kvh * HD + i;
  float x1 = bf2f(C[cb]), x2 = bf2f(C[cb + 64]);
  float c = cosT[(s << 6) + i], sn = sinT[(s << 6) + i];
  size_t ob = ((size_t)(b * NKVH + kvh) * SEQL + s) * HD + i;
  kr[ob]      = f2bf(x1 * c - x2 * sn);
  kr[ob + 64] = f2bf(x2 * c + x1 * sn);
}

// ---------------- V transpose: -> vt[b][kvh][d][s] ----------------
__global__ void k_vt(const u16* __restrict__ C, u16* __restrict__ vt) {
  int idx = blockIdx.x * 256 + threadIdx.x;
  int s = idx & (SEQL - 1);
  int d = (idx >> 11) & 127;
  int kvh = (idx >> 18) & 3;
  int b = idx >> 20;
  int m = b * SEQL + s;
  vt[idx] = C[(size_t)m * NQKV + 2560 + kvh * HD + d];
}

// ---------------- flash attention: window=512, softcap, GQA ----------------
// No-online-softmax variant: softcap bounds |s|<=50, so p=exp(s) is always
// representable (e^+-50 within f32/bf16 range); l and O scale identically and
// O/l is exact. Eliminates max-tracking, alpha, O-rescale, per-tile shuffles.
// 64-kv tiles, single-buffered K/V (m114: 3 blocks/CU hide the drain),
// interior tiles skip masking. P bounced via padded LDS (fixed addrs).
__global__ __launch_bounds__(256, 3) void k_attn(const u16* __restrict__ qr,
                                                 const u16* __restrict__ kr,
                                                 const u16* __restrict__ vt,
                                                 u16* __restrict__ ao) {
  __shared__ __align__(16) u16 kbuf[64 * 128];    // [kv][d], chunk ^= row&7
  __shared__ __align__(16) u16 vbuf[128 * 64];    // [d][kv], chunk ^= row&7
  __shared__ __align__(16) u16 plds[4][16 * 72];  // P bounce, rows padded to 72

  const int t = threadIdx.x;
  const int wid = t >> 6, lane = t & 63, lr = lane & 15, lk = lane >> 4;
  const int h = blockIdx.x, bq = blockIdx.y, b = blockIdx.z;
  const int kvh = h >> 2;
  const int Q0 = bq * 64;
  const int q0w = Q0 + wid * 16;
  const u16* qb = qr + (size_t)(b * NH + h) * SEQL * HD;
  const u16* kb = kr + (size_t)(b * NKVH + kvh) * SEQL * HD;
  const u16* vb = vt + (size_t)(b * NKVH + kvh) * HD * SEQL;

  // Q as B-frag: lane holds Q[q0w+lr][kc*32 + lk*8 + j]
  short8 qf[4];
  #pragma unroll
  for (int kc = 0; kc < 4; ++kc)
    qf[kc] = *(const short8*)(qb + (size_t)(q0w + lr) * HD + kc * 32 + lk * 8);

  f32x4 o[8];
  #pragma unroll
  for (int dt = 0; dt < 8; ++dt) o[dt] = f32x4{0.f, 0.f, 0.f, 0.f};
  float lsum = 0.f;                       // per-lane partial for q = q0w + lr

  int lo = Q0 - (WIN - 1); if (lo < 0) lo = 0;
  const int t_lo = lo >> 6, t_hi = (Q0 + 63) >> 6;

  u16* pw = plds[wid];

  for (int kt = t_lo; kt <= t_hi; ++kt) {
    const int kv0 = kt << 6;
    __syncthreads();                      // previous tile's reads complete
    #pragma unroll
    for (int i = 0; i < 4; ++i) {         // stage K(16KB) + V^T(16KB), pre-swizzled src
      const int C = i * 256 + t;
      const int krw = C >> 4, kcc = C & 15;
      gld16(kb + (size_t)(kv0 + krw) * HD + ((kcc ^ (krw & 7)) << 3), &kbuf[C << 3]);
      const int vrw = C >> 3, vcc = C & 7;
      gld16(vb + (size_t)vrw * SEQL + kv0 + ((vcc ^ (vrw & 7)) << 3), &vbuf[C << 3]);
    }
    __syncthreads();                      // drain + visibility
    if (kv0 + 63 < q0w - (WIN - 1) || kv0 > q0w + 15) continue;  // wave-uniform skip

    // QK^T swapped: A = K rows, B = Q. sv[g] holds S^T[kv0+g*16+lk*4+r][q0w+lr]
    f32x4 sv[4];
    #pragma unroll
    for (int g = 0; g < 4; ++g) sv[g] = f32x4{0.f, 0.f, 0.f, 0.f};
    #pragma unroll
    for (int g = 0; g < 4; ++g) {
      const u16* krow = kbuf + ((g * 16 + lr) << 7);
      #pragma unroll
      for (int kc = 0; kc < 4; ++kc) {
        short8 kf = *(const short8*)(krow + ((((kc << 2) + lk) ^ (lr & 7)) << 3));
        sv[g] = __builtin_amdgcn_mfma_f32_16x16x32_bf16(kf, qf[kc], sv[g], 0, 0, 0);
      }
    }

    // p = exp(softcap(s)) directly; no max subtraction needed (|s| <= 50)
    float p[4][4];
    const bool interior = (kv0 + 63 <= q0w) && (kv0 >= q0w + 16 - WIN);
    if (interior) {
      #pragma unroll
      for (int g = 0; g < 4; ++g)
        #pragma unroll
        for (int r = 0; r < 4; ++r)
          p[g][r] = __expf(softcap_f(sv[g][r] * QKSCALE));
    } else {
      const int qg = q0w + lr;
      #pragma unroll
      for (int g = 0; g < 4; ++g)
        #pragma unroll
        for (int r = 0; r < 4; ++r) {
          const int kg = kv0 + g * 16 + lk * 4 + r;
          float s = softcap_f(sv[g][r] * QKSCALE);
          p[g][r] = (kg <= qg && kg > qg - WIN) ? __expf(s) : 0.f;
        }
    }
    #pragma unroll
    for (int g = 0; g < 4; ++g)
      lsum += (p[g][0] + p[g][1]) + (p[g][2] + p[g][3]);

    // pack p -> bf16 pairs, bounce through plds to A-frag layout (fixed addrs)
    #pragma unroll
    for (int g = 0; g < 4; ++g) {
      __hip_bfloat162 u0 = __float22bfloat162_rn(float2{p[g][0], p[g][1]});
      __hip_bfloat162 u1 = __float22bfloat162_rn(float2{p[g][2], p[g][3]});
      uint2 w;
      w.x = *(uint32_t*)&u0; w.y = *(uint32_t*)&u1;
      *(uint2*)(pw + lr * 72 + g * 16 + lk * 4) = w;   // kv = 16g+4lk..+3, q-row lr
    }
    short8 pf0 = *(const short8*)(pw + lr * 72 + lk * 8);        // kv 0..31 chunk
    short8 pf1 = *(const short8*)(pw + lr * 72 + 32 + lk * 8);   // kv 32..63 chunk

    // PV: A = P, B = V^T rows. o[dt][r] = O[q=lk*4+r][d=dt*16+lr]
    #pragma unroll
    for (int m = 0; m < 2; ++m) {
      const short8 pf = m ? pf1 : pf0;
      #pragma unroll
      for (int dt = 0; dt < 8; ++dt) {
        const int vr = dt * 16 + lr;
        short8 vf = *(const short8*)(vbuf + (vr << 6) + (((m * 4 + lk) ^ (lr & 7)) << 3));
        o[dt] = __builtin_amdgcn_mfma_f32_16x16x32_bf16(pf, vf, o[dt], 0, 0, 0);
      }
    }
  }

  // epilogue: reduce lsum over the 4 lanes sharing q (lr, lr+16, lr+32, lr+48)
  lsum += __shfl_xor(lsum, 16);
  lsum += __shfl_xor(lsum, 32);
  float linv = 1.0f / lsum;               // for q = q0w + lr
  #pragma unroll
  for (int r = 0; r < 4; ++r) {
    float inv = __shfl(linv, lk * 4 + r); // redistribute to output layout
    const int srow = q0w + lk * 4 + r;
    u16* op = ao + (size_t)(b * SEQL + srow) * DM + h * HD;
    #pragma unroll
    for (int dt = 0; dt < 8; ++dt) op[dt * 16 + lr] = f2bf(o[dt][r] * inv);
  }
}

extern "C" void kernel_launch(void* const* d_in, const int* in_sizes, int n_in,
                              void* d_out, int out_size, void* d_ws, size_t ws_size,
                              hipStream_t stream) {
  (void)in_sizes; (void)n_in; (void)out_size; (void)ws_size;
  const float* hs = (const float*)d_in[0];
  const float* wq = (const float*)d_in[1];
  const float* wk = (const float*)d_in[2];
  const float* wv = (const float*)d_in[3];
  const float* wo = (const float*)d_in[4];
  float* out = (float*)d_out;

  u16* ws    = (u16*)d_ws;
  u16* A_bf  = ws;                      //  8,388,608  hs bf16 [4096][2048]
  u16* Wqkv  = A_bf + 8388608;          //  6,291,456  packed [3072][2048]
  u16* Cqkv  = Wqkv + 6291456;          // 12,582,912  [4096][3072]
  u16* q_r   = Cqkv + 12582912;         //  8,388,608  [b][h][s][128]
  u16* k_r   = q_r + 8388608;           //  2,097,152  [b][kvh][s][128]
  u16* vTb   = k_r + 2097152;           //  2,097,152  [b][kvh][128][s]
  float* cosT = (float*)(vTb + 2097152);
  float* sinT = cosT + 131072;
  u16* Wo   = Cqkv;                     // reuse Cqkv after rope/vt consume it
  u16* aout = A_bf;                     // reuse A_bf after QKV gemm

  k_cast<<<8192, 256, 0, stream>>>(hs, A_bf, 2097152);
  k_cast<<<4096, 256, 0, stream>>>(wq, Wqkv, 1048576);
  k_cast<<<1024, 256, 0, stream>>>(wk, Wqkv + 4194304, 262144);
  k_cast<<<1024, 256, 0, stream>>>(wv, Wqkv + 5242880, 262144);
  k_rope_table<<<2048, 64, 0, stream>>>(cosT, sinT);

  k_gemm_bt<u16><<<dim3(NQKV / 128, MR / 128), 256, 0, stream>>>(A_bf, Wqkv, Cqkv, NQKV, DM);

  k_rope_q<<<16384, 256, 0, stream>>>(Cqkv, cosT, sinT, q_r);
  k_rope_k<<<4096, 256, 0, stream>>>(Cqkv, cosT, sinT, k_r);
  k_vt<<<8192, 256, 0, stream>>>(Cqkv, vTb);
  k_cast<<<4096, 256, 0, stream>>>(wo, Wo, 1048576);

  k_attn<<<dim3(NH, SEQL / 64, BAT), 256, 0, stream>>>(q_r, k_r, vTb, aout);

  k_gemm_bt<float><<<dim3(DM / 128, MR / 128), 256, 0, stream>>>(aout, Wo, out, DM, DM);
}

// Round 7
// 189.353 us; speedup vs baseline: 1.8650x; 1.0633x over previous
//
#include <hip/hip_runtime.h>
#include <hip/hip_bf16.h>
#include <stdint.h>

// Problem constants
#define DM    2048
#define NH    16
#define NKVH  4
#define HD    128
#define WIN   512
#define SEQL  2048
#define BAT   2
#define MR    (BAT*SEQL)        // 4096 rows
#define NQKV  3072              // 2048 q + 512 k + 512 v
#define QKSCALE 0.08838834764831845f
#define CAP   50.0f
// C1: folded into Q at RoPE. sv = y * 2*log2e/CAP where y = q.k*QKSCALE
#define C1F (QKSCALE * 2.0f * 1.4426950408889634f / CAP)
#define C2F (-144.26950408889634f)   // -2*CAP*log2e ; p' = 2^(C2F/(2^sv+1))

typedef unsigned short u16;
typedef __attribute__((ext_vector_type(8))) short short8;
typedef __attribute__((ext_vector_type(4))) float f32x4;

__device__ __forceinline__ u16 f2bf(float f) {
  union { float f; uint32_t u; } v; v.f = f;
  uint32_t r = v.u + 0x7FFFu + ((v.u >> 16) & 1u);
  return (u16)(r >> 16);
}
__device__ __forceinline__ float bf2f(u16 h) {
  union { uint32_t u; float f; } v; v.u = ((uint32_t)h) << 16; return v.f;
}
__device__ __forceinline__ void gld16(const void* g, void* l) {
  __builtin_amdgcn_global_load_lds((const __attribute__((address_space(1))) void*)g,
                                   (__attribute__((address_space(3))) void*)l,
                                   16, 0, 0);
}
// p' = exp(CAP*tanh(y/CAP)) / e^CAP, with sv = y*2*log2e/CAP (C1 pre-folded into Q).
// = 2^( C2F / (2^sv + 1) ). Uses REAL intrinsics (not inline asm) so the
// compiler's hazard recognizer inserts the TRANS-op wait states (R6 NaN fix).
__device__ __forceinline__ float exp_softcap(float sv) {
  float t = __builtin_amdgcn_exp2f(sv);
  float u = __builtin_amdgcn_rcpf(t + 1.0f);
  return __builtin_amdgcn_exp2f(u * C2F);
}

// ---------------- elementwise: fp32 -> bf16 cast ----------------
__global__ void k_cast(const float* __restrict__ src, u16* __restrict__ dst, int n4) {
  int i = blockIdx.x * 256 + threadIdx.x;
  if (i >= n4) return;
  float4 v = ((const float4*)src)[i];
  ushort4 o;
  o.x = f2bf(v.x); o.y = f2bf(v.y); o.z = f2bf(v.z); o.w = f2bf(v.w);
  ((ushort4*)dst)[i] = o;
}

// ---------------- RoPE cos/sin table: [S][64] ----------------
__global__ void k_rope_table(float* __restrict__ c, float* __restrict__ sn) {
  int s = blockIdx.x, i = threadIdx.x;
  float invf = expf(-(float)i * (9.210340371976184f / 64.0f));
  float a = (float)s * invf;
  c[(s << 6) + i]  = cosf(a);
  sn[(s << 6) + i] = sinf(a);
}

// ---------------- GEMM: C[M][N] = A[M][K] * B[N][K]^T (unchanged, ~940 TF) ----------------
template <typename OutT>
__global__ __launch_bounds__(256, 3) void k_gemm_bt(const u16* __restrict__ A,
                                                    const u16* __restrict__ Bm,
                                                    OutT* __restrict__ C,
                                                    int N, int K) {
  __shared__ __align__(16) u16 ldsA[128 * 64];
  __shared__ __align__(16) u16 ldsB[128 * 64];
  const int t = threadIdx.x;

  const int nwg  = gridDim.x * gridDim.y;
  const int flat = blockIdx.y * gridDim.x + blockIdx.x;
  const int cpx  = nwg >> 3;
  const int swz  = (flat & 7) * cpx + (flat >> 3);
  const int bn = swz % gridDim.x, bm = swz / gridDim.x;

  const int m0 = bm * 128, n0 = bn * 128;
  const int lane = t & 63, wid = t >> 6;
  const int lr = lane & 15, lk = lane >> 4;
  const int wr = (wid >> 1) * 64, wc = (wid & 1) * 64;
  const int nt = K >> 6;

  const int srow = t >> 3;
  const int scol = (((t & 7) ^ (srow & 7)) << 3);

  f32x4 acc[4][4];
  #pragma unroll
  for (int mi = 0; mi < 4; ++mi)
    #pragma unroll
    for (int ni = 0; ni < 4; ++ni) acc[mi][ni] = f32x4{0.f, 0.f, 0.f, 0.f};

  for (int kt = 0; kt < nt; ++kt) {
    {
      const u16* a0 = A  + (size_t)(m0 + srow) * K + kt * 64 + scol;
      const u16* b0 = Bm + (size_t)(n0 + srow) * K + kt * 64 + scol;
      #pragma unroll
      for (int i = 0; i < 4; ++i) {
        gld16(a0 + (size_t)(i * 32) * K, &ldsA[i * 2048 + t * 8]);
        gld16(b0 + (size_t)(i * 32) * K, &ldsB[i * 2048 + t * 8]);
      }
    }
    __syncthreads();
    #pragma unroll
    for (int ks = 0; ks < 2; ++ks) {
      const int c = ks * 4 + lk;
      short8 af[4], bfv[4];
      #pragma unroll
      for (int mi = 0; mi < 4; ++mi) {
        const int ra = wr + mi * 16 + lr;
        af[mi] = *(const short8*)(ldsA + ra * 64 + ((c ^ (ra & 7)) << 3));
      }
      #pragma unroll
      for (int ni = 0; ni < 4; ++ni) {
        const int rb = wc + ni * 16 + lr;
        bfv[ni] = *(const short8*)(ldsB + rb * 64 + ((c ^ (rb & 7)) << 3));
      }
      #pragma unroll
      for (int mi = 0; mi < 4; ++mi)
        #pragma unroll
        for (int ni = 0; ni < 4; ++ni)
          acc[mi][ni] = __builtin_amdgcn_mfma_f32_16x16x32_bf16(af[mi], bfv[ni], acc[mi][ni], 0, 0, 0);
    }
    if (kt + 1 < nt) __syncthreads();
  }

  #pragma unroll
  for (int mi = 0; mi < 4; ++mi) {
    #pragma unroll
    for (int ni = 0; ni < 4; ++ni) {
      const int r0 = m0 + wr + mi * 16 + lk * 4;
      const int c  = n0 + wc + ni * 16 + lr;
      #pragma unroll
      for (int r = 0; r < 4; ++r) {
        float v = acc[mi][ni][r];
        if constexpr (__is_same(OutT, float)) C[(size_t)(r0 + r) * N + c] = v;
        else                                  C[(size_t)(r0 + r) * N + c] = f2bf(v);
      }
    }
  }
}

// ---------------- RoPE on Q (pre-scaled by C1F for the attn softcap-exp) ----------------
__global__ void k_rope_q(const u16* __restrict__ C, const float* __restrict__ cosT,
                         const float* __restrict__ sinT, u16* __restrict__ qr) {
  int idx = blockIdx.x * 256 + threadIdx.x;
  int i = idx & 63, hh = (idx >> 6) & 15, m = idx >> 10;
  int s = m & (SEQL - 1), b = m >> 11;
  size_t cb = (size_t)m * NQKV + hh * HD + i;
  float x1 = bf2f(C[cb]), x2 = bf2f(C[cb + 64]);
  float c = cosT[(s << 6) + i], sn = sinT[(s << 6) + i];
  size_t ob = ((size_t)(b * NH + hh) * SEQL + s) * HD + i;
  qr[ob]      = f2bf((x1 * c - x2 * sn) * C1F);
  qr[ob + 64] = f2bf((x2 * c + x1 * sn) * C1F);
}

// ---------------- RoPE on K ----------------
__global__ void k_rope_k(const u16* __restrict__ C, const float* __restrict__ cosT,
                         const float* __restrict__ sinT, u16* __restrict__ kr) {
  int idx = blockIdx.x * 256 + threadIdx.x;
  int i = idx & 63, kvh = (idx >> 6) & 3, m = idx >> 8;
  int s = m & (SEQL - 1), b = m >> 11;
  size_t cb = (size_t)m * NQKV + 2048 + kvh * HD + i;
  float x1 = bf2f(C[cb]), x2 = bf2f(C[cb + 64]);
  float c = cosT[(s << 6) + i], sn = sinT[(s << 6) + i];
  size_t ob = ((size_t)(b * NKVH + kvh) * SEQL + s) * HD + i;
  kr[ob]      = f2bf(x1 * c - x2 * sn);
  kr[ob + 64] = f2bf(x2 * c + x1 * sn);
}

// ---------------- V transpose: -> vt[b][kvh][d][s] ----------------
__global__ void k_vt(const u16* __restrict__ C, u16* __restrict__ vt) {
  int idx = blockIdx.x * 256 + threadIdx.x;
  int s = idx & (SEQL - 1);
  int d = (idx >> 11) & 127;
  int kvh = (idx >> 18) & 3;
  int b = idx >> 20;
  int m = b * SEQL + s;
  vt[idx] = C[(size_t)m * NQKV + 2560 + kvh * HD + d];
}

// ---------------- flash attention: window=512, softcap, GQA ----------------
// 32-kv tiles, double-buffered K/V staging, 4 blocks/CU (37.9KB LDS). No online
// softmax (softcap bounds scores; e^CAP factored out, cancels in O/l). Cheap
// softcap-exp: 3 trans + 2 VALU per score via builtin exp2/rcp; C1 folded into Q.
__global__ __launch_bounds__(256, 4) void k_attn(const u16* __restrict__ qr,
                                                 const u16* __restrict__ kr,
                                                 const u16* __restrict__ vt,
                                                 u16* __restrict__ ao) {
  __shared__ __align__(16) u16 kbuf[2][32 * 128];   // [kv][d], byte bits[6:4]^=row&7
  __shared__ __align__(16) u16 vbuf[2][128 * 32];   // [d][kv], byte bits[5:4]^=(row>>1)&3
  __shared__ __align__(16) u16 plds[4][16 * 40];    // P bounce, rows padded to 40 u16

  const int t = threadIdx.x;
  const int wid = t >> 6, lane = t & 63, lr = lane & 15, lk = lane >> 4;
  const int h = blockIdx.x, bq = blockIdx.y, b = blockIdx.z;
  const int kvh = h >> 2;
  const int Q0 = bq * 64;
  const int q0w = Q0 + wid * 16;
  const u16* qb = qr + (size_t)(b * NH + h) * SEQL * HD;
  const u16* kb = kr + (size_t)(b * NKVH + kvh) * SEQL * HD;
  const u16* vb = vt + (size_t)(b * NKVH + kvh) * HD * SEQL;

  // Q as B-frag (pre-scaled by C1F): lane holds Q[q0w+lr][kc*32 + lk*8 + j]
  short8 qf[4];
  #pragma unroll
  for (int kc = 0; kc < 4; ++kc)
    qf[kc] = *(const short8*)(qb + (size_t)(q0w + lr) * HD + kc * 32 + lk * 8);

  f32x4 o[8];
  #pragma unroll
  for (int dt = 0; dt < 8; ++dt) o[dt] = f32x4{0.f, 0.f, 0.f, 0.f};
  float lsum = 0.f;                       // per-lane partial for q = q0w + lr

  int lo = Q0 - (WIN - 1); if (lo < 0) lo = 0;
  const int ktlo = lo >> 5, kthi = (Q0 + 63) >> 5;

  auto stageK = [&](int bufi, int kv0) {
    #pragma unroll
    for (int i = 0; i < 2; ++i) {
      int c = t + i * 256;
      int bb = c << 4;
      int sb = bb ^ (((bb >> 8) & 7) << 4);   // involution on bits [6:4]
      gld16(kb + (size_t)(kv0 + (sb >> 8)) * HD + ((sb & 255) >> 1),
            &kbuf[bufi][c << 3]);
    }
  };
  auto stageV = [&](int bufi, int kv0) {
    #pragma unroll
    for (int i = 0; i < 2; ++i) {
      int c = t + i * 256;
      int bb = c << 4;
      int sb = bb ^ (((bb >> 7) & 3) << 4);   // involution on bits [5:4]
      gld16(vb + (size_t)(sb >> 6) * SEQL + kv0 + ((sb & 63) >> 1),
            &vbuf[bufi][c << 3]);
    }
  };

  stageK(0, ktlo << 5);
  stageV(0, ktlo << 5);
  __syncthreads();

  u16* pw = plds[wid];

  for (int kt = ktlo; kt <= kthi; ++kt) {
    const int cur = kt & 1;
    if (kt < kthi) { stageK(cur ^ 1, (kt + 1) << 5); stageV(cur ^ 1, (kt + 1) << 5); }
    const int kv0 = kt << 5;
    if (kv0 + 31 >= q0w - (WIN - 1) && kv0 <= q0w + 15) {   // wave-uniform skip
      // QK^T swapped: A = K rows (lr, lr+16), B = Q  -> lane owns q-row lr
      f32x4 sv0 = f32x4{0.f, 0.f, 0.f, 0.f}, sv1 = sv0;
      const u16* lks = kbuf[cur];
      #pragma unroll
      for (int kc = 0; kc < 4; ++kc) {
        int b0 = (lr * 256 + kc * 64 + lk * 16) ^ ((lr & 7) << 4);
        int b1 = ((lr + 16) * 256 + kc * 64 + lk * 16) ^ ((lr & 7) << 4);
        short8 k0 = *(const short8*)(lks + (b0 >> 1));
        short8 k1 = *(const short8*)(lks + (b1 >> 1));
        sv0 = __builtin_amdgcn_mfma_f32_16x16x32_bf16(k0, qf[kc], sv0, 0, 0, 0);
        sv1 = __builtin_amdgcn_mfma_f32_16x16x32_bf16(k1, qf[kc], sv1, 0, 0, 0);
      }
      // p' = exp(softcap)/e^CAP; no max tracking needed
      float p[8];
      #pragma unroll
      for (int r = 0; r < 4; ++r) {
        p[r]     = exp_softcap(sv0[r]);
        p[r + 4] = exp_softcap(sv1[r]);
      }
      const bool interior = (kv0 + 31 <= q0w) && (kv0 >= q0w + 16 - WIN);
      if (!interior) {
        const int qg = q0w + lr;
        #pragma unroll
        for (int r = 0; r < 4; ++r) {
          int kg0 = kv0 + lk * 4 + r, kg1 = kg0 + 16;
          if (!(kg0 <= qg && kg0 > qg - WIN)) p[r] = 0.f;
          if (!(kg1 <= qg && kg1 > qg - WIN)) p[r + 4] = 0.f;
        }
      }
      lsum += ((p[0] + p[1]) + (p[2] + p[3])) + ((p[4] + p[5]) + (p[6] + p[7]));
      // pack p -> plds (q-row lr, kv cols lk*4.. / 16+lk*4..), 40-u16 padded rows
      __hip_bfloat162 u0 = __float22bfloat162_rn(float2{p[0], p[1]});
      __hip_bfloat162 u1 = __float22bfloat162_rn(float2{p[2], p[3]});
      __hip_bfloat162 u2 = __float22bfloat162_rn(float2{p[4], p[5]});
      __hip_bfloat162 u3 = __float22bfloat162_rn(float2{p[6], p[7]});
      uint2 w0; w0.x = *(uint32_t*)&u0; w0.y = *(uint32_t*)&u1;
      uint2 w1; w1.x = *(uint32_t*)&u2; w1.y = *(uint32_t*)&u3;
      *(uint2*)(pw + lr * 40 + lk * 4)      = w0;
      *(uint2*)(pw + lr * 40 + 16 + lk * 4) = w1;
      // PV: A = P (a-frag), B = V^T rows from swizzled vbuf
      short8 pf = *(const short8*)(pw + lr * 40 + lk * 8);
      const u16* lvs = vbuf[cur];
      #pragma unroll
      for (int dt = 0; dt < 8; ++dt) {
        int row = dt * 16 + lr;
        int bb = (row * 64 + lk * 16) ^ (((row >> 1) & 3) << 4);
        o[dt] = __builtin_amdgcn_mfma_f32_16x16x32_bf16(pf, *(const short8*)(lvs + (bb >> 1)), o[dt], 0, 0, 0);
      }
    }
    __syncthreads();
  }

  // epilogue: reduce lsum over the 4 lanes sharing q (lr, lr+16, lr+32, lr+48)
  lsum += __shfl_xor(lsum, 16);
  lsum += __shfl_xor(lsum, 32);
  float linv = 1.0f / lsum;               // for q = q0w + lr
  #pragma unroll
  for (int r = 0; r < 4; ++r) {
    float inv = __shfl(linv, lk * 4 + r); // redistribute to output layout
    const int srow = q0w + lk * 4 + r;
    u16* op = ao + (size_t)(b * SEQL + srow) * DM + h * HD;
    #pragma unroll
    for (int dt = 0; dt < 8; ++dt) op[dt * 16 + lr] = f2bf(o[dt][r] * inv);
  }
}

extern "C" void kernel_launch(void* const* d_in, const int* in_sizes, int n_in,
                              void* d_out, int out_size, void* d_ws, size_t ws_size,
                              hipStream_t stream) {
  (void)in_sizes; (void)n_in; (void)out_size; (void)ws_size;
  const float* hs = (const float*)d_in[0];
  const float* wq = (const float*)d_in[1];
  const float* wk = (const float*)d_in[2];
  const float* wv = (const float*)d_in[3];
  const float* wo = (const float*)d_in[4];
  float* out = (float*)d_out;

  u16* ws    = (u16*)d_ws;
  u16* A_bf  = ws;                      //  8,388,608  hs bf16 [4096][2048]
  u16* Wqkv  = A_bf + 8388608;          //  6,291,456  packed [3072][2048]
  u16* Cqkv  = Wqkv + 6291456;          // 12,582,912  [4096][3072]
  u16* q_r   = Cqkv + 12582912;         //  8,388,608  [b][h][s][128]
  u16* k_r   = q_r + 8388608;           //  2,097,152  [b][kvh][s][128]
  u16* vTb   = k_r + 2097152;           //  2,097,152  [b][kvh][128][s]
  float* cosT = (float*)(vTb + 2097152);
  float* sinT = cosT + 131072;
  u16* Wo   = Cqkv;                     // reuse Cqkv after rope/vt consume it
  u16* aout = A_bf;                     // reuse A_bf after QKV gemm

  k_cast<<<8192, 256, 0, stream>>>(hs, A_bf, 2097152);
  k_cast<<<4096, 256, 0, stream>>>(wq, Wqkv, 1048576);
  k_cast<<<1024, 256, 0, stream>>>(wk, Wqkv + 4194304, 262144);
  k_cast<<<1024, 256, 0, stream>>>(wv, Wqkv + 5242880, 262144);
  k_rope_table<<<2048, 64, 0, stream>>>(cosT, sinT);

  k_gemm_bt<u16><<<dim3(NQKV / 128, MR / 128), 256, 0, stream>>>(A_bf, Wqkv, Cqkv, NQKV, DM);

  k_rope_q<<<16384, 256, 0, stream>>>(Cqkv, cosT, sinT, q_r);
  k_rope_k<<<4096, 256, 0, stream>>>(Cqkv, cosT, sinT, k_r);
  k_vt<<<8192, 256, 0, stream>>>(Cqkv, vTb);
  k_cast<<<4096, 256, 0, stream>>>(wo, Wo, 1048576);

  k_attn<<<dim3(NH, SEQL / 64, BAT), 256, 0, stream>>>(q_r, k_r, vTb, aout);

  k_gemm_bt<float><<<dim3(DM / 128, MR / 128), 256, 0, stream>>>(aout, Wo, out, DM, DM);
}